// Round 10
// baseline (450.000 us; speedup 1.0000x reference)
//
#include <hip/hip_runtime.h>
#include <math.h>

// ---------------------------------------------------------------------------
// MultiModalFusionGAT — round 10
//   = round 9 (64-row LDS tiles, B prefetch ring, online-softmax edge kernel)
//   + fully-coalesced C-stores: MFMA outputs staged through LDS, then written
//     as contiguous rows (kills the 1.5x partial-cacheline write amplification
//     seen as WRITE_SIZE 120MB vs 79MB logical).
// ---------------------------------------------------------------------------

namespace {
constexpr int HIDN  = 128;
constexpr int NHEAD = 8;

constexpr int NU = 20000, NI = 50000, NT = 50000, NG = 50000;
constexpr int E_TI = 50000, E_IM = 50000, E_UB = 500000, E_BU = 500000;
constexpr int ETOT = E_TI + E_IM + E_UB + E_BU;   // 1,100,000
constexpr int ND   = NI + NU;                     // dst nodes: items then users

constexpr int BASE_U = 0;
constexpr int BASE_I = NU;
constexpr int BASE_T = NU + NI;
constexpr int BASE_G = NU + NI + NT;

constexpr int NMAT = 12;           // 0..3 k, 4..7 v, 8/9 q(user,item), 10/11 Wo(item,user)
constexpr int MATSZ = 128 * 128;
constexpr int XP = 132;            // float stride for LDS tiles
constexpr int SU = 136;            // ushort stride for bf16 staging

constexpr int NBU = (NU + 63) / 64;
constexpr int NBI = (NI + 63) / 64;
constexpr int NBT = (NT + 63) / 64;
constexpr int NBG = (NG + 63) / 64;
}

typedef __attribute__((ext_vector_type(8))) short short8v;
typedef __attribute__((ext_vector_type(4))) float f32x4;

__device__ __forceinline__ unsigned short bf16rne(float f) {
    unsigned u = __float_as_uint(f);
    unsigned r = (u + 0x7fffu + ((u >> 16) & 1u)) >> 16;
    return (unsigned short)r;
}
__device__ __forceinline__ float bf16f(unsigned short h) {
    return __uint_as_float(((unsigned)h) << 16);
}
__device__ __forceinline__ float bflo(unsigned int u) { return __uint_as_float(u << 16); }
__device__ __forceinline__ float bfhi(unsigned int u) { return __uint_as_float(u & 0xffff0000u); }

// cw layout: [which(2)][type(4)][row(129)][col(128)]; row 128 = transformed bias
__global__ void build_cw_kernel(const float* __restrict__ Wk, const float* __restrict__ bk,
                                const float* __restrict__ Wv, const float* __restrict__ bv,
                                const float* __restrict__ a_rel, const float* __restrict__ m_rel,
                                float* __restrict__ cw)
{
    const int total = 2 * 4 * 129 * 128;
    int idx = blockIdx.x * blockDim.x + threadIdx.x;
    if (idx >= total) return;
    int c     = idx & 127;
    int r     = (idx >> 7) % 129;
    int t     = ((idx >> 7) / 129) & 3;
    int which = idx / (4 * 129 * 128);
    const int et_map[4] = {2, 3, 0, 1};
    int et = et_map[t];
    const float* W = (which == 0 ? Wk : Wv) + (size_t)t * HIDN * HIDN;
    const float* b = (which == 0 ? bk : bv) + (size_t)t * HIDN;
    const float* A = (which == 0 ? a_rel : m_rel) + (size_t)et * NHEAD * 16 * 16;
    int h = c >> 4, e2 = c & 15;
    float s = 0.f;
#pragma unroll
    for (int d = 0; d < 16; ++d) {
        float w = (r == 128) ? b[h * 16 + d] : W[(size_t)r * HIDN + h * 16 + d];
        s = fmaf(w, A[h * 256 + d * 16 + e2], s);
    }
    cw[idx] = s;
}

__global__ void pack_kernel(const float* __restrict__ cw,
                            const float* __restrict__ Wq, const float* __restrict__ bq,
                            const float* __restrict__ Wo, const float* __restrict__ bo,
                            short* __restrict__ pkh, short* __restrict__ pkl,
                            float* __restrict__ bias)
{
    const int total = NMAT * MATSZ + NMAT * HIDN;
    int idx = blockIdx.x * blockDim.x + threadIdx.x;
    if (idx >= total) return;
    if (idx < NMAT * MATSZ) {
        int mat = idx >> 14;
        int rem = idx & (MATSZ - 1);
        int i    = rem & 7;
        int lane = (rem >> 3) & 63;
        int ct   = (rem >> 9) & 7;
        int ks   = rem >> 12;
        int k   = ks * 32 + ((lane >> 4) & 3) * 8 + i;
        int col = ct * 16 + (lane & 15);
        float v;
        if (mat < 8)       v = cw[(size_t)mat * 129 * 128 + (size_t)k * 128 + col];
        else if (mat < 10) v = Wq[(size_t)(mat - 8) * MATSZ + (size_t)k * 128 + col];
        else               v = Wo[(size_t)(mat - 10) * MATSZ + (size_t)k * 128 + col];
        unsigned short hb = bf16rne(v);
        float rest = v - bf16f(hb);
        pkh[idx] = (short)hb;
        pkl[idx] = (short)bf16rne(rest);
    } else {
        int b = idx - NMAT * MATSZ;
        int mat = b >> 7, col = b & 127;
        float v;
        if (mat < 8)       v = cw[(size_t)mat * 129 * 128 + (size_t)128 * 128 + col];
        else if (mat < 10) v = bq[(mat - 8) * HIDN + col];
        else               v = bo[(mat - 10) * HIDN + col];
        bias[b] = v;
    }
}

// All four node types in one launch; 64-row tiles, 16 rows/wave,
// B prefetch ring, LDS-staged coalesced C-stores.
__global__ __launch_bounds__(256) void mfma_proj_all(
    const float* __restrict__ xu, const float* __restrict__ xi,
    const float* __restrict__ xt, const float* __restrict__ xg,
    const short* __restrict__ pkh, const short* __restrict__ pkl,
    const float* __restrict__ bias,
    unsigned short* __restrict__ krb, unsigned short* __restrict__ vrb,
    float* __restrict__ q_u, float* __restrict__ q_i)
{
    int b = blockIdx.x;
    int seg, bloc;
    if (b < NBU)                  { seg = 0; bloc = b; }
    else if (b < NBU + NBI)       { seg = 1; bloc = b - NBU; }
    else if (b < NBU + NBI + NBT) { seg = 2; bloc = b - NBU - NBI; }
    else                          { seg = 3; bloc = b - NBU - NBI - NBT; }
    const float* x = (seg == 0) ? xu : (seg == 1) ? xi : (seg == 2) ? xt : xg;
    const int M     = (seg == 0) ? NU : (seg == 1) ? NI : (seg == 2) ? NT : NG;
    const int rbase = (seg == 0) ? BASE_U : (seg == 1) ? BASE_I : (seg == 2) ? BASE_T : BASE_G;
    float* qp = (seg == 0) ? q_u : (seg == 1) ? q_i : nullptr;

    __shared__ float xs[64 * XP];
    unsigned short* xsu = (unsigned short*)xs;   // bf16 staging view, stride SU
    const int t  = threadIdx.x;
    const int r0 = bloc * 64;
    const int rows = min(64, M - r0);

#pragma unroll
    for (int p = 0; p < 8; ++p) {
        int f = p * 256 + t;
        int row = f >> 5, c4 = f & 31;
        float4 v = make_float4(0.f, 0.f, 0.f, 0.f);
        if (row < rows) v = *(const float4*)(x + (size_t)(r0 + row) * HIDN + c4 * 4);
        *(float4*)&xs[row * XP + c4 * 4] = v;
    }
    __syncthreads();

    const int l = t & 63, w = t >> 6;
    const int arow = w * 16 + (l & 15);
    const int kgrp = l >> 4;

    short8v ahi[4], alo[4];
#pragma unroll
    for (int ks = 0; ks < 4; ++ks) {
        const float* xp = &xs[arow * XP + ks * 32 + kgrp * 8];
        float4 va = *(const float4*)xp;
        float4 vb = *(const float4*)(xp + 4);
        float vv[8] = {va.x, va.y, va.z, va.w, vb.x, vb.y, vb.z, vb.w};
#pragma unroll
        for (int i = 0; i < 8; ++i) {
            unsigned short hb = bf16rne(vv[i]);
            ahi[ks][i] = (short)hb;
            alo[ks][i] = (short)bf16rne(vv[i] - bf16f(hb));
        }
    }

    for (int mi = 0; mi < 3; ++mi) {
        if (mi == 2 && qp == nullptr) break;
        const int mat = (mi == 0) ? seg : (mi == 1) ? (4 + seg) : (8 + seg);
        const short8v* bh = (const short8v*)(pkh + (size_t)mat * MATSZ);
        const short8v* bl = (const short8v*)(pkl + (size_t)mat * MATSZ);
        const float*   bs = bias + mat * HIDN;

        f32x4 acc[8];
        f32x4 z; z[0] = 0.f; z[1] = 0.f; z[2] = 0.f; z[3] = 0.f;
#pragma unroll
        for (int ct = 0; ct < 8; ++ct) acc[ct] = z;

        // B prefetch ring, distance 4. it = ks*8 + ct.
        short8v pb1[4], pb2[4];
#pragma unroll
        for (int pi = 0; pi < 4; ++pi) {
            pb1[pi] = bh[pi * 64 + l];
            pb2[pi] = bl[pi * 64 + l];
        }
#pragma unroll
        for (int it = 0; it < 32; ++it) {
            const int ks = it >> 3, ct = it & 7;
            short8v b1 = pb1[it & 3], b2 = pb2[it & 3];
            if (it + 4 < 32) {
                pb1[it & 3] = bh[(it + 4) * 64 + l];
                pb2[it & 3] = bl[(it + 4) * 64 + l];
            }
            acc[ct] = __builtin_amdgcn_mfma_f32_16x16x32_bf16(ahi[ks], b1, acc[ct], 0, 0, 0);
            acc[ct] = __builtin_amdgcn_mfma_f32_16x16x32_bf16(alo[ks], b1, acc[ct], 0, 0, 0);
            acc[ct] = __builtin_amdgcn_mfma_f32_16x16x32_bf16(ahi[ks], b2, acc[ct], 0, 0, 0);
        }

        const int crow0 = w * 16 + kgrp * 4;
        const int ccol  = l & 15;
        __syncthreads();   // xs (A-tile / previous coop-store) reads done
        if (mi < 2) {
            // stage bf16 tile in LDS, then coalesced row stores
#pragma unroll
            for (int ct = 0; ct < 8; ++ct) {
                float bv = bs[ct * 16 + ccol];
#pragma unroll
                for (int j = 0; j < 4; ++j)
                    xsu[(crow0 + j) * SU + ct * 16 + ccol] = bf16rne(acc[ct][j] + bv);
            }
            __syncthreads();
            unsigned short* dst = (mi == 0) ? krb : vrb;
            unsigned int* dstw = (unsigned int*)(dst + (size_t)(rbase + r0) * HIDN);
#pragma unroll
            for (int p = 0; p < 16; ++p) {
                int f = p * 256 + t;
                int row = f >> 6, c = f & 63;
                if (row < rows)
                    dstw[(size_t)row * 64 + c] = *(const unsigned int*)&xsu[row * SU + 2 * c];
            }
        } else {
            // stage fp32 q tile, coalesced float4 stores
#pragma unroll
            for (int ct = 0; ct < 8; ++ct) {
                float bv = bs[ct * 16 + ccol];
#pragma unroll
                for (int j = 0; j < 4; ++j)
                    xs[(crow0 + j) * XP + ct * 16 + ccol] = acc[ct][j] + bv;
            }
            __syncthreads();
            float4* qp4 = (float4*)(qp + (size_t)r0 * HIDN);
#pragma unroll
            for (int p = 0; p < 8; ++p) {
                int f = p * 256 + t;
                int row = f >> 5, c4 = f & 31;
                if (row < rows)
                    qp4[(size_t)row * 32 + c4] = *(const float4*)&xs[row * XP + c4 * 4];
            }
        }
    }
}

// Both epilogues in one launch; LDS-staged coalesced stores + coalesced xin reads.
__global__ __launch_bounds__(256) void mfma_out_all(
    const float* __restrict__ agg_i, const float* __restrict__ agg_u,
    const short* __restrict__ pkh, const short* __restrict__ pkl,
    const float* __restrict__ bias,
    const float* __restrict__ x_item, const float* __restrict__ x_user,
    const float* __restrict__ skip_ptr,
    float* __restrict__ outp)
{
    int b = blockIdx.x;
    int seg = (b < NBI) ? 0 : 1;
    int bloc = (seg == 0) ? b : b - NBI;
    const float* agg = (seg == 0) ? agg_i : agg_u;
    const float* xin = (seg == 0) ? x_item : x_user;
    const int M = (seg == 0) ? NI : NU;
    const int mat = 10 + seg;
    float* out = (seg == 0) ? outp : outp + (size_t)NI * HIDN;

    __shared__ float xs[64 * XP];
    const int t  = threadIdx.x;
    const int r0 = bloc * 64;
    const int rows = min(64, M - r0);

#pragma unroll
    for (int p = 0; p < 8; ++p) {
        int f = p * 256 + t;
        int row = f >> 5, c4 = f & 31;
        float4 v = make_float4(0.f, 0.f, 0.f, 0.f);
        if (row < rows) v = *(const float4*)(agg + (size_t)(r0 + row) * HIDN + c4 * 4);
        *(float4*)&xs[row * XP + c4 * 4] = v;
    }
    __syncthreads();

    const int l = t & 63, w = t >> 6;
    const int arow = w * 16 + (l & 15);
    const int kgrp = l >> 4;

    short8v ahi[4], alo[4];
#pragma unroll
    for (int ks = 0; ks < 4; ++ks) {
        const float* xp = &xs[arow * XP + ks * 32 + kgrp * 8];
        float4 va = *(const float4*)xp;
        float4 vb = *(const float4*)(xp + 4);
        float vv[8] = {va.x, va.y, va.z, va.w, vb.x, vb.y, vb.z, vb.w};
#pragma unroll
        for (int i = 0; i < 8; ++i) {
            float g = 0.5f * vv[i] * (1.0f + erff(vv[i] * 0.70710678118654752440f));
            unsigned short hb = bf16rne(g);
            ahi[ks][i] = (short)hb;
            alo[ks][i] = (short)bf16rne(g - bf16f(hb));
        }
    }

    const short8v* bh = (const short8v*)(pkh + (size_t)mat * MATSZ);
    const short8v* bl = (const short8v*)(pkl + (size_t)mat * MATSZ);
    const float*   bs = bias + mat * HIDN;

    f32x4 acc[8];
    f32x4 z; z[0] = 0.f; z[1] = 0.f; z[2] = 0.f; z[3] = 0.f;
#pragma unroll
    for (int ct = 0; ct < 8; ++ct) acc[ct] = z;

    short8v pb1[4], pb2[4];
#pragma unroll
    for (int pi = 0; pi < 4; ++pi) {
        pb1[pi] = bh[pi * 64 + l];
        pb2[pi] = bl[pi * 64 + l];
    }
#pragma unroll
    for (int it = 0; it < 32; ++it) {
        const int ks = it >> 3, ct = it & 7;
        short8v b1 = pb1[it & 3], b2 = pb2[it & 3];
        if (it + 4 < 32) {
            pb1[it & 3] = bh[(it + 4) * 64 + l];
            pb2[it & 3] = bl[(it + 4) * 64 + l];
        }
        acc[ct] = __builtin_amdgcn_mfma_f32_16x16x32_bf16(ahi[ks], b1, acc[ct], 0, 0, 0);
        acc[ct] = __builtin_amdgcn_mfma_f32_16x16x32_bf16(alo[ks], b1, acc[ct], 0, 0, 0);
        acc[ct] = __builtin_amdgcn_mfma_f32_16x16x32_bf16(ahi[ks], b2, acc[ct], 0, 0, 0);
    }

    const float gate = 1.f / (1.f + expf(-skip_ptr[seg]));
    const int crow0 = w * 16 + kgrp * 4;
    const int ccol  = l & 15;
    __syncthreads();
#pragma unroll
    for (int ct = 0; ct < 8; ++ct) {
        float bv = bs[ct * 16 + ccol];
#pragma unroll
        for (int j = 0; j < 4; ++j)
            xs[(crow0 + j) * XP + ct * 16 + ccol] = acc[ct][j] + bv;
    }
    __syncthreads();
    const float4* xin4 = (const float4*)(xin + (size_t)r0 * HIDN);
    float4* out4 = (float4*)(out + (size_t)r0 * HIDN);
    const float og = 1.f - gate;
#pragma unroll
    for (int p = 0; p < 8; ++p) {
        int f = p * 256 + t;
        int row = f >> 5, c4 = f & 31;
        if (row < rows) {
            float4 v = *(const float4*)&xs[row * XP + c4 * 4];
            float4 xi = xin4[(size_t)row * 32 + c4];
            float4 o;
            o.x = gate * v.x + og * xi.x;
            o.y = gate * v.y + og * xi.y;
            o.z = gate * v.z + og * xi.z;
            o.w = gate * v.w + og * xi.w;
            out4[(size_t)row * 32 + c4] = o;
        }
    }
}

// ----------------------- CSR construction -----------------------

__global__ void hist_kernel(const int* __restrict__ ti_dst, const int* __restrict__ im_dst,
                            const int* __restrict__ ub_dst, const int* __restrict__ bu_dst,
                            int* __restrict__ deg)
{
    int i = blockIdx.x * blockDim.x + threadIdx.x;
    if (i >= ETOT) return;
    int d;
    if (i < E_TI)                     d = ti_dst[i];
    else if (i < E_TI + E_IM)         d = im_dst[i - E_TI];
    else if (i < E_TI + E_IM + E_UB)  d = ub_dst[i - E_TI - E_IM];
    else                              d = NI + bu_dst[i - E_TI - E_IM - E_UB];
    atomicAdd(&deg[d], 1);
}

__global__ void scan1_kernel(int* __restrict__ deg, int* __restrict__ tops, int n)
{
    __shared__ int sh[256];
    int i = blockIdx.x * 256 + threadIdx.x;
    int v = (i < n) ? deg[i] : 0;
    sh[threadIdx.x] = v;
    __syncthreads();
    for (int o = 1; o < 256; o <<= 1) {
        int t = (threadIdx.x >= o) ? sh[threadIdx.x - o] : 0;
        __syncthreads();
        sh[threadIdx.x] += t;
        __syncthreads();
    }
    if (i < n) deg[i] = sh[threadIdx.x];
    if (threadIdx.x == 255) tops[blockIdx.x] = sh[255];
}

__global__ void scan2_kernel(int* __restrict__ tops, int nb)
{
    __shared__ int sh[1024];
    int v = (threadIdx.x < nb) ? tops[threadIdx.x] : 0;
    sh[threadIdx.x] = v;
    __syncthreads();
    for (int o = 1; o < 1024; o <<= 1) {
        int t = (threadIdx.x >= o) ? sh[threadIdx.x - o] : 0;
        __syncthreads();
        sh[threadIdx.x] += t;
        __syncthreads();
    }
    if (threadIdx.x < nb) tops[threadIdx.x] = sh[threadIdx.x];
}

__global__ void scan3_kernel(const int* __restrict__ part, const int* __restrict__ tops,
                             int* __restrict__ rowptr, int* __restrict__ cursor, int n)
{
    int i = blockIdx.x * 256 + threadIdx.x;
    if (i >= n) return;
    int add = (blockIdx.x > 0) ? tops[blockIdx.x - 1] : 0;
    int prev = (i > 0) ? ((threadIdx.x > 0) ? part[i - 1] + add
                                            : ((blockIdx.x > 0) ? tops[blockIdx.x - 1] : 0))
                       : 0;
    rowptr[i + 1] = part[i] + add;
    cursor[i] = prev;
    if (i == 0) rowptr[0] = 0;
}

// col entry: (src_row << 2) | edge_type
__global__ void scatter_kernel(const int* __restrict__ ti_src, const int* __restrict__ ti_dst,
                               const int* __restrict__ im_src, const int* __restrict__ im_dst,
                               const int* __restrict__ ub_src, const int* __restrict__ ub_dst,
                               const int* __restrict__ bu_src, const int* __restrict__ bu_dst,
                               int* __restrict__ cursor, int* __restrict__ col)
{
    int i = blockIdx.x * blockDim.x + threadIdx.x;
    if (i >= ETOT) return;
    int d, row, et;
    if (i < E_TI)                    { d = ti_dst[i];                 row = BASE_T + ti_src[i];                 et = 0; }
    else if (i < E_TI + E_IM)        { int e = i - E_TI;              row = BASE_G + im_src[e]; d = im_dst[e];  et = 1; }
    else if (i < E_TI + E_IM + E_UB) { int e = i - E_TI - E_IM;       row = BASE_U + ub_src[e]; d = ub_dst[e];  et = 2; }
    else                             { int e = i - E_TI - E_IM - E_UB; row = BASE_I + bu_src[e]; d = NI + bu_dst[e]; et = 3; }
    int p = atomicAdd(&cursor[d], 1);
    col[p] = (row << 2) | et;
}

// ------------------- fused edge softmax-attention (online, one pass) -------------------
__global__ __launch_bounds__(256) void f12_kernel(
    const int* __restrict__ rowptr, const int* __restrict__ rowend,
    const int* __restrict__ col,
    const unsigned int* __restrict__ krw,   // bf16x2 per uint, row stride 64
    const float* __restrict__ q_i, const float* __restrict__ q_u,
    const unsigned int* __restrict__ vrw,
    const float* __restrict__ prel,
    float* __restrict__ agg_i, float* __restrict__ agg_u)
{
    int wid = (blockIdx.x << 2) + (threadIdx.x >> 6);
    if (wid >= ND) return;
    const int l = threadIdx.x & 63;
    const int h = l >> 3;

    const float* qrow = (wid < NI) ? q_i + (size_t)wid * HIDN
                                   : q_u + (size_t)(wid - NI) * HIDN;
    float2 qv = *(const float2*)(qrow + 2 * l);
    const float pr0 = prel[h]      * 0.25f;
    const float pr1 = prel[8 + h]  * 0.25f;
    const float pr2 = prel[16 + h] * 0.25f;
    const float pr3 = prel[24 + h] * 0.25f;

    const int start = rowptr[wid], end = rowend[wid];
    float m = -3.0e38f, ax = 0.f, ay = 0.f, den = 0.f;

    int p = start;
    for (; p + 1 < end; p += 2) {
        int pk0 = col[p], pk1 = col[p + 1];
        unsigned int u0 = krw[(size_t)(pk0 >> 2) * 64 + l];
        unsigned int u1 = krw[(size_t)(pk1 >> 2) * 64 + l];
        unsigned int v0 = vrw[(size_t)(pk0 >> 2) * 64 + l];
        unsigned int v1 = vrw[(size_t)(pk1 >> 2) * 64 + l];
        float d0 = qv.x * bflo(u0) + qv.y * bfhi(u0);
        float d1 = qv.x * bflo(u1) + qv.y * bfhi(u1);
        d0 += __shfl_xor(d0, 1); d1 += __shfl_xor(d1, 1);
        d0 += __shfl_xor(d0, 2); d1 += __shfl_xor(d1, 2);
        d0 += __shfl_xor(d0, 4); d1 += __shfl_xor(d1, 4);
        int e0t = pk0 & 3, e1t = pk1 & 3;
        float f0 = (e0t & 2) ? ((e0t & 1) ? pr3 : pr2) : ((e0t & 1) ? pr1 : pr0);
        float f1 = (e1t & 2) ? ((e1t & 1) ? pr3 : pr2) : ((e1t & 1) ? pr1 : pr0);
        float a0 = d0 * f0;
        float a1 = d1 * f1;
        float mn = fmaxf(m, fmaxf(a0, a1));
        float s  = __expf(m - mn);
        float e0 = __expf(a0 - mn);
        float e1 = __expf(a1 - mn);
        ax = ax * s + e0 * bflo(v0) + e1 * bflo(v1);
        ay = ay * s + e0 * bfhi(v0) + e1 * bfhi(v1);
        den = den * s + e0 + e1;
        m = mn;
    }
    if (p < end) {
        int pk0 = col[p];
        unsigned int u0 = krw[(size_t)(pk0 >> 2) * 64 + l];
        unsigned int v0 = vrw[(size_t)(pk0 >> 2) * 64 + l];
        float d0 = qv.x * bflo(u0) + qv.y * bfhi(u0);
        d0 += __shfl_xor(d0, 1);
        d0 += __shfl_xor(d0, 2);
        d0 += __shfl_xor(d0, 4);
        int e0t = pk0 & 3;
        float f0 = (e0t & 2) ? ((e0t & 1) ? pr3 : pr2) : ((e0t & 1) ? pr1 : pr0);
        float a0 = d0 * f0;
        float mn = fmaxf(m, a0);
        float s  = __expf(m - mn);
        float e0 = __expf(a0 - mn);
        ax = ax * s + e0 * bflo(v0);
        ay = ay * s + e0 * bfhi(v0);
        den = den * s + e0;
    }

    float inv = 1.f / (den + 1e-16f);
    float* dst = (wid < NI) ? agg_i + (size_t)wid * HIDN
                            : agg_u + (size_t)(wid - NI) * HIDN;
    *(float2*)(dst + 2 * l) = make_float2(ax * inv, ay * inv);
}

extern "C" void kernel_launch(void* const* d_in, const int* in_sizes, int n_in,
                              void* d_out, int out_size, void* d_ws, size_t ws_size,
                              hipStream_t stream)
{
    const float* x_user = (const float*)d_in[0];
    const float* x_item = (const float*)d_in[1];
    const float* x_taste= (const float*)d_in[2];
    const float* x_image= (const float*)d_in[3];
    const float* Wk     = (const float*)d_in[4];
    const float* bk     = (const float*)d_in[5];
    const float* Wq     = (const float*)d_in[6];
    const float* bq     = (const float*)d_in[7];
    const float* Wv     = (const float*)d_in[8];
    const float* bv     = (const float*)d_in[9];
    const float* a_rel  = (const float*)d_in[10];
    const float* m_rel  = (const float*)d_in[11];
    const float* p_rel  = (const float*)d_in[12];
    const float* Wo     = (const float*)d_in[13];
    const float* bo     = (const float*)d_in[14];
    const float* skip   = (const float*)d_in[15];
    const int* ti_src = (const int*)d_in[16];
    const int* ti_dst = (const int*)d_in[17];
    const int* im_src = (const int*)d_in[18];
    const int* im_dst = (const int*)d_in[19];
    const int* ub_src = (const int*)d_in[20];
    const int* ub_dst = (const int*)d_in[21];
    const int* bu_src = (const int*)d_in[22];
    const int* bu_dst = (const int*)d_in[23];

    float* ws = (float*)d_ws;
    float* outp = (float*)d_out;
    (void)in_sizes; (void)n_in; (void)out_size;

    // ---- workspace layout (floats) ----
    size_t off = 0;
    auto alloc = [&](size_t n) { size_t o = off; off += n; return o; };
    const size_t o_cw   = alloc((size_t)2 * 4 * 129 * 128);   // reused as deg[] after pack
    const size_t o_pkh  = alloc((size_t)NMAT * MATSZ / 2);
    const size_t o_pkl  = alloc((size_t)NMAT * MATSZ / 2);
    const size_t o_bias = alloc((size_t)NMAT * HIDN);
    const size_t o_krb  = alloc((size_t)(NU + NI + NT + NG) * HIDN / 2);  // bf16 table
    const size_t o_vrb  = alloc((size_t)(NU + NI + NT + NG) * HIDN / 2);  // bf16 table
    const size_t o_q_i  = alloc((size_t)NI * HIDN);
    const size_t o_q_u  = alloc((size_t)NU * HIDN);
    const size_t o_agg  = alloc((size_t)(NI + NU) * HIDN);
    const size_t o_int  = alloc((size_t)(ND + 1) + ND + 1024 + ETOT);

    if (ws_size < off * sizeof(float)) return;  // clean failure instead of OOB fault

    unsigned short* krb = (unsigned short*)(ws + o_krb);
    unsigned short* vrb = (unsigned short*)(ws + o_vrb);

    short* pkh  = (short*)(ws + o_pkh);
    short* pkl  = (short*)(ws + o_pkl);
    float* bias = ws + o_bias;

    int* deg    = (int*)(ws + o_cw);        // overlays cw (dead after pack)
    int* rowptr = (int*)(ws + o_int);
    int* cursor = rowptr + (ND + 1);
    int* tops   = cursor + ND;
    int* col    = tops + 1024;

    float* agg_i = ws + o_agg;
    float* agg_u = ws + o_agg + (size_t)NI * HIDN;

    // ---- 1. combined weights + MFMA pack ----
    {
        int total = 2 * 4 * 129 * 128;
        build_cw_kernel<<<(total + 255) / 256, 256, 0, stream>>>(
            Wk, bk, Wv, bv, a_rel, m_rel, ws + o_cw);
        int ptotal = NMAT * MATSZ + NMAT * HIDN;
        pack_kernel<<<(ptotal + 255) / 256, 256, 0, stream>>>(
            ws + o_cw, Wq, bq, Wo, bo, pkh, pkl, bias);
    }

    // ---- 2. projections ----
    mfma_proj_all<<<NBU + NBI + NBT + NBG, 256, 0, stream>>>(
        x_user, x_item, x_taste, x_image, pkh, pkl, bias,
        krb, vrb, ws + o_q_u, ws + o_q_i);

    // ---- 3. CSR build ----
    hipMemsetAsync(deg, 0, ND * sizeof(int), stream);
    hist_kernel<<<(ETOT + 255) / 256, 256, 0, stream>>>(ti_dst, im_dst, ub_dst, bu_dst, deg);
    const int NB1 = (ND + 255) / 256;
    scan1_kernel<<<NB1, 256, 0, stream>>>(deg, tops, ND);
    scan2_kernel<<<1, 1024, 0, stream>>>(tops, NB1);
    scan3_kernel<<<NB1, 256, 0, stream>>>(deg, tops, rowptr, cursor, ND);
    scatter_kernel<<<(ETOT + 255) / 256, 256, 0, stream>>>(
        ti_src, ti_dst, im_src, im_dst, ub_src, ub_dst, bu_src, bu_dst, cursor, col);
    // after scatter, cursor[d] == row end

    // ---- 4. fused online-softmax edge aggregation ----
    const int NBW = (ND + 3) / 4;
    f12_kernel<<<NBW, 256, 0, stream>>>(
        rowptr, cursor, col,
        (const unsigned int*)krb, ws + o_q_i, ws + o_q_u,
        (const unsigned int*)vrb, p_rel,
        agg_i, agg_u);

    // ---- 5. epilogue ----
    mfma_out_all<<<NBI + NBU, 256, 0, stream>>>(
        agg_i, agg_u, pkh, pkl, bias, x_item, x_user, skip, outp);
}

// Round 11
// 398.115 us; speedup vs baseline: 1.1303x; 1.1303x over previous
//
#include <hip/hip_runtime.h>
#include <math.h>

// ---------------------------------------------------------------------------
// MultiModalFusionGAT — round 11
//   Projections/epilogue: B-STATIONARY split-bf16 MFMA.
//     Wave owns 2 column-tiles; B-fragments (64 VGPR) loaded once per mat;
//     A staged in LDS as pre-split bf16 hi/lo planes; inner loop =
//     2 ds_read_b128 + 6 MFMA, no L2 dependency. 4x less B L2 traffic.
//   Edge phase / CSR: unchanged from round 9 (best: 412 us).
// ---------------------------------------------------------------------------

namespace {
constexpr int HIDN  = 128;
constexpr int NHEAD = 8;

constexpr int NU = 20000, NI = 50000, NT = 50000, NG = 50000;
constexpr int E_TI = 50000, E_IM = 50000, E_UB = 500000, E_BU = 500000;
constexpr int ETOT = E_TI + E_IM + E_UB + E_BU;   // 1,100,000
constexpr int ND   = NI + NU;                     // dst nodes: items then users

constexpr int BASE_U = 0;
constexpr int BASE_I = NU;
constexpr int BASE_T = NU + NI;
constexpr int BASE_G = NU + NI + NT;

constexpr int NMAT = 12;           // 0..3 k, 4..7 v, 8/9 q(user,item), 10/11 Wo(item,user)
constexpr int MATSZ = 128 * 128;
constexpr int SU = 136;            // ushort stride for hi/lo LDS planes

constexpr int NBU = (NU + 63) / 64;
constexpr int NBI = (NI + 63) / 64;
constexpr int NBT = (NT + 63) / 64;
constexpr int NBG = (NG + 63) / 64;
}

typedef __attribute__((ext_vector_type(8))) short short8v;
typedef __attribute__((ext_vector_type(4))) float f32x4;
typedef __attribute__((ext_vector_type(4))) unsigned short ushort4v;

__device__ __forceinline__ unsigned short bf16rne(float f) {
    unsigned u = __float_as_uint(f);
    unsigned r = (u + 0x7fffu + ((u >> 16) & 1u)) >> 16;
    return (unsigned short)r;
}
__device__ __forceinline__ float bf16f(unsigned short h) {
    return __uint_as_float(((unsigned)h) << 16);
}
__device__ __forceinline__ float bflo(unsigned int u) { return __uint_as_float(u << 16); }
__device__ __forceinline__ float bfhi(unsigned int u) { return __uint_as_float(u & 0xffff0000u); }

// cw layout: [which(2)][type(4)][row(129)][col(128)]; row 128 = transformed bias
__global__ void build_cw_kernel(const float* __restrict__ Wk, const float* __restrict__ bk,
                                const float* __restrict__ Wv, const float* __restrict__ bv,
                                const float* __restrict__ a_rel, const float* __restrict__ m_rel,
                                float* __restrict__ cw)
{
    const int total = 2 * 4 * 129 * 128;
    int idx = blockIdx.x * blockDim.x + threadIdx.x;
    if (idx >= total) return;
    int c     = idx & 127;
    int r     = (idx >> 7) % 129;
    int t     = ((idx >> 7) / 129) & 3;
    int which = idx / (4 * 129 * 128);
    const int et_map[4] = {2, 3, 0, 1};
    int et = et_map[t];
    const float* W = (which == 0 ? Wk : Wv) + (size_t)t * HIDN * HIDN;
    const float* b = (which == 0 ? bk : bv) + (size_t)t * HIDN;
    const float* A = (which == 0 ? a_rel : m_rel) + (size_t)et * NHEAD * 16 * 16;
    int h = c >> 4, e2 = c & 15;
    float s = 0.f;
#pragma unroll
    for (int d = 0; d < 16; ++d) {
        float w = (r == 128) ? b[h * 16 + d] : W[(size_t)r * HIDN + h * 16 + d];
        s = fmaf(w, A[h * 256 + d * 16 + e2], s);
    }
    cw[idx] = s;
}

__global__ void pack_kernel(const float* __restrict__ cw,
                            const float* __restrict__ Wq, const float* __restrict__ bq,
                            const float* __restrict__ Wo, const float* __restrict__ bo,
                            short* __restrict__ pkh, short* __restrict__ pkl,
                            float* __restrict__ bias)
{
    const int total = NMAT * MATSZ + NMAT * HIDN;
    int idx = blockIdx.x * blockDim.x + threadIdx.x;
    if (idx >= total) return;
    if (idx < NMAT * MATSZ) {
        int mat = idx >> 14;
        int rem = idx & (MATSZ - 1);
        int i    = rem & 7;
        int lane = (rem >> 3) & 63;
        int ct   = (rem >> 9) & 7;
        int ks   = rem >> 12;
        int k   = ks * 32 + ((lane >> 4) & 3) * 8 + i;
        int col = ct * 16 + (lane & 15);
        float v;
        if (mat < 8)       v = cw[(size_t)mat * 129 * 128 + (size_t)k * 128 + col];
        else if (mat < 10) v = Wq[(size_t)(mat - 8) * MATSZ + (size_t)k * 128 + col];
        else               v = Wo[(size_t)(mat - 10) * MATSZ + (size_t)k * 128 + col];
        unsigned short hb = bf16rne(v);
        float rest = v - bf16f(hb);
        pkh[idx] = (short)hb;
        pkl[idx] = (short)bf16rne(rest);
    } else {
        int b = idx - NMAT * MATSZ;
        int mat = b >> 7, col = b & 127;
        float v;
        if (mat < 8)       v = cw[(size_t)mat * 129 * 128 + (size_t)128 * 128 + col];
        else if (mat < 10) v = bq[(mat - 8) * HIDN + col];
        else               v = bo[(mat - 10) * HIDN + col];
        bias[b] = v;
    }
}

// B-stationary projections: all four node types in one launch, 64-row tiles.
// Wave w owns column-tiles {2w, 2w+1}; B-frags in registers; A hi/lo in LDS.
__global__ __launch_bounds__(256) void mfma_proj_all(
    const float* __restrict__ xu, const float* __restrict__ xi,
    const float* __restrict__ xt, const float* __restrict__ xg,
    const short* __restrict__ pkh, const short* __restrict__ pkl,
    const float* __restrict__ bias,
    unsigned short* __restrict__ krb, unsigned short* __restrict__ vrb,
    float* __restrict__ q_u, float* __restrict__ q_i)
{
    int b = blockIdx.x;
    int seg, bloc;
    if (b < NBU)                  { seg = 0; bloc = b; }
    else if (b < NBU + NBI)       { seg = 1; bloc = b - NBU; }
    else if (b < NBU + NBI + NBT) { seg = 2; bloc = b - NBU - NBI; }
    else                          { seg = 3; bloc = b - NBU - NBI - NBT; }
    const float* x = (seg == 0) ? xu : (seg == 1) ? xi : (seg == 2) ? xt : xg;
    const int M     = (seg == 0) ? NU : (seg == 1) ? NI : (seg == 2) ? NT : NG;
    const int rbase = (seg == 0) ? BASE_U : (seg == 1) ? BASE_I : (seg == 2) ? BASE_T : BASE_G;
    float* qp = (seg == 0) ? q_u : (seg == 1) ? q_i : nullptr;

    __shared__ unsigned short hs[64 * SU];
    __shared__ unsigned short ls[64 * SU];
    const int t  = threadIdx.x;
    const int r0 = bloc * 64;
    const int rows = min(64, M - r0);

    // stage A pre-split into bf16 hi/lo planes (cvt paid once per block)
#pragma unroll
    for (int p = 0; p < 8; ++p) {
        int f = p * 256 + t;          // 2048 float4 slots
        int row = f >> 5, c4 = f & 31;
        float4 v = make_float4(0.f, 0.f, 0.f, 0.f);
        if (row < rows) v = *(const float4*)(x + (size_t)(r0 + row) * HIDN + c4 * 4);
        float vv[4] = {v.x, v.y, v.z, v.w};
        ushort4v hq, lq;
#pragma unroll
        for (int i = 0; i < 4; ++i) {
            unsigned short hb = bf16rne(vv[i]);
            hq[i] = hb;
            lq[i] = bf16rne(vv[i] - bf16f(hb));
        }
        *(ushort4v*)&hs[row * SU + c4 * 4] = hq;
        *(ushort4v*)&ls[row * SU + c4 * 4] = lq;
    }
    __syncthreads();

    const int l = t & 63, w = t >> 6;
    const int kgrp = l >> 4;
    const int ct0  = 2 * w;
    const int ccol = l & 15;

    for (int mi = 0; mi < 3; ++mi) {
        if (mi == 2 && qp == nullptr) break;
        const int mat = (mi == 0) ? seg : (mi == 1) ? (4 + seg) : (8 + seg);
        const short8v* bh = (const short8v*)(pkh + (size_t)mat * MATSZ);
        const short8v* bl = (const short8v*)(pkl + (size_t)mat * MATSZ);
        const float*   bs = bias + mat * HIDN;

        // B stationary: 2 ct x 4 ks, hi+lo  (64 VGPR), loaded once per mat
        short8v B1[4][2], B2[4][2];
#pragma unroll
        for (int ks = 0; ks < 4; ++ks) {
#pragma unroll
            for (int c = 0; c < 2; ++c) {
                B1[ks][c] = bh[(ks * 8 + ct0 + c) * 64 + l];
                B2[ks][c] = bl[(ks * 8 + ct0 + c) * 64 + l];
            }
        }

        const float bv0 = bs[(ct0 + 0) * 16 + ccol];
        const float bv1 = bs[(ct0 + 1) * 16 + ccol];

        for (int rt = 0; rt < 4; ++rt) {
            f32x4 a0, a1;
            a0[0]=0.f;a0[1]=0.f;a0[2]=0.f;a0[3]=0.f;
            a1[0]=0.f;a1[1]=0.f;a1[2]=0.f;a1[3]=0.f;
            const int arow = rt * 16 + ccol;
#pragma unroll
            for (int ks = 0; ks < 4; ++ks) {
                short8v ah = *(const short8v*)&hs[arow * SU + ks * 32 + kgrp * 8];
                short8v al = *(const short8v*)&ls[arow * SU + ks * 32 + kgrp * 8];
                a0 = __builtin_amdgcn_mfma_f32_16x16x32_bf16(ah, B1[ks][0], a0, 0, 0, 0);
                a1 = __builtin_amdgcn_mfma_f32_16x16x32_bf16(ah, B1[ks][1], a1, 0, 0, 0);
                a0 = __builtin_amdgcn_mfma_f32_16x16x32_bf16(al, B1[ks][0], a0, 0, 0, 0);
                a1 = __builtin_amdgcn_mfma_f32_16x16x32_bf16(al, B1[ks][1], a1, 0, 0, 0);
                a0 = __builtin_amdgcn_mfma_f32_16x16x32_bf16(ah, B2[ks][0], a0, 0, 0, 0);
                a1 = __builtin_amdgcn_mfma_f32_16x16x32_bf16(ah, B2[ks][1], a1, 0, 0, 0);
            }
            const int crow = r0 + rt * 16 + kgrp * 4;
            if (mi < 2) {
                unsigned short* dst = (mi == 0) ? krb : vrb;
#pragma unroll
                for (int j = 0; j < 4; ++j) {
                    int grow = crow + j;
                    if (grow < M) {
                        size_t o = (size_t)(rbase + grow) * HIDN;
                        dst[o + (ct0 + 0) * 16 + ccol] = bf16rne(a0[j] + bv0);
                        dst[o + (ct0 + 1) * 16 + ccol] = bf16rne(a1[j] + bv1);
                    }
                }
            } else {
#pragma unroll
                for (int j = 0; j < 4; ++j) {
                    int grow = crow + j;
                    if (grow < M) {
                        size_t o = (size_t)grow * HIDN;
                        qp[o + (ct0 + 0) * 16 + ccol] = a0[j] + bv0;
                        qp[o + (ct0 + 1) * 16 + ccol] = a1[j] + bv1;
                    }
                }
            }
        }
    }
}

// B-stationary epilogue: both outputs in one launch.
__global__ __launch_bounds__(256) void mfma_out_all(
    const float* __restrict__ agg_i, const float* __restrict__ agg_u,
    const short* __restrict__ pkh, const short* __restrict__ pkl,
    const float* __restrict__ bias,
    const float* __restrict__ x_item, const float* __restrict__ x_user,
    const float* __restrict__ skip_ptr,
    float* __restrict__ outp)
{
    int b = blockIdx.x;
    int seg = (b < NBI) ? 0 : 1;
    int bloc = (seg == 0) ? b : b - NBI;
    const float* agg = (seg == 0) ? agg_i : agg_u;
    const float* xin = (seg == 0) ? x_item : x_user;
    const int M = (seg == 0) ? NI : NU;
    const int mat = 10 + seg;
    float* out = (seg == 0) ? outp : outp + (size_t)NI * HIDN;

    __shared__ unsigned short hs[64 * SU];
    __shared__ unsigned short ls[64 * SU];
    const int t  = threadIdx.x;
    const int r0 = bloc * 64;
    const int rows = min(64, M - r0);

#pragma unroll
    for (int p = 0; p < 8; ++p) {
        int f = p * 256 + t;
        int row = f >> 5, c4 = f & 31;
        float4 v = make_float4(0.f, 0.f, 0.f, 0.f);
        if (row < rows) v = *(const float4*)(agg + (size_t)(r0 + row) * HIDN + c4 * 4);
        float vv[4] = {v.x, v.y, v.z, v.w};
        ushort4v hq, lq;
#pragma unroll
        for (int i = 0; i < 4; ++i) {
            float g = 0.5f * vv[i] * (1.0f + erff(vv[i] * 0.70710678118654752440f));
            unsigned short hb = bf16rne(g);
            hq[i] = hb;
            lq[i] = bf16rne(g - bf16f(hb));
        }
        *(ushort4v*)&hs[row * SU + c4 * 4] = hq;
        *(ushort4v*)&ls[row * SU + c4 * 4] = lq;
    }
    __syncthreads();

    const int l = t & 63, w = t >> 6;
    const int kgrp = l >> 4;
    const int ct0  = 2 * w;
    const int ccol = l & 15;

    const short8v* bh = (const short8v*)(pkh + (size_t)mat * MATSZ);
    const short8v* bl = (const short8v*)(pkl + (size_t)mat * MATSZ);
    const float*   bs = bias + mat * HIDN;

    short8v B1[4][2], B2[4][2];
#pragma unroll
    for (int ks = 0; ks < 4; ++ks) {
#pragma unroll
        for (int c = 0; c < 2; ++c) {
            B1[ks][c] = bh[(ks * 8 + ct0 + c) * 64 + l];
            B2[ks][c] = bl[(ks * 8 + ct0 + c) * 64 + l];
        }
    }

    const float gate = 1.f / (1.f + expf(-skip_ptr[seg]));
    const float og = 1.f - gate;
    const float bv0 = bs[(ct0 + 0) * 16 + ccol];
    const float bv1 = bs[(ct0 + 1) * 16 + ccol];

    for (int rt = 0; rt < 4; ++rt) {
        f32x4 a0, a1;
        a0[0]=0.f;a0[1]=0.f;a0[2]=0.f;a0[3]=0.f;
        a1[0]=0.f;a1[1]=0.f;a1[2]=0.f;a1[3]=0.f;
        const int arow = rt * 16 + ccol;
#pragma unroll
        for (int ks = 0; ks < 4; ++ks) {
            short8v ah = *(const short8v*)&hs[arow * SU + ks * 32 + kgrp * 8];
            short8v al = *(const short8v*)&ls[arow * SU + ks * 32 + kgrp * 8];
            a0 = __builtin_amdgcn_mfma_f32_16x16x32_bf16(ah, B1[ks][0], a0, 0, 0, 0);
            a1 = __builtin_amdgcn_mfma_f32_16x16x32_bf16(ah, B1[ks][1], a1, 0, 0, 0);
            a0 = __builtin_amdgcn_mfma_f32_16x16x32_bf16(al, B1[ks][0], a0, 0, 0, 0);
            a1 = __builtin_amdgcn_mfma_f32_16x16x32_bf16(al, B1[ks][1], a1, 0, 0, 0);
            a0 = __builtin_amdgcn_mfma_f32_16x16x32_bf16(ah, B2[ks][0], a0, 0, 0, 0);
            a1 = __builtin_amdgcn_mfma_f32_16x16x32_bf16(ah, B2[ks][1], a1, 0, 0, 0);
        }
        const int crow = r0 + rt * 16 + kgrp * 4;
#pragma unroll
        for (int j = 0; j < 4; ++j) {
            int grow = crow + j;
            if (grow < M) {
                size_t o = (size_t)grow * HIDN;
                size_t o0 = o + (ct0 + 0) * 16 + ccol;
                size_t o1 = o + (ct0 + 1) * 16 + ccol;
                out[o0] = gate * (a0[j] + bv0) + og * xin[o0];
                out[o1] = gate * (a1[j] + bv1) + og * xin[o1];
            }
        }
    }
}

// ----------------------- CSR construction -----------------------

__global__ void hist_kernel(const int* __restrict__ ti_dst, const int* __restrict__ im_dst,
                            const int* __restrict__ ub_dst, const int* __restrict__ bu_dst,
                            int* __restrict__ deg)
{
    int i = blockIdx.x * blockDim.x + threadIdx.x;
    if (i >= ETOT) return;
    int d;
    if (i < E_TI)                     d = ti_dst[i];
    else if (i < E_TI + E_IM)         d = im_dst[i - E_TI];
    else if (i < E_TI + E_IM + E_UB)  d = ub_dst[i - E_TI - E_IM];
    else                              d = NI + bu_dst[i - E_TI - E_IM - E_UB];
    atomicAdd(&deg[d], 1);
}

__global__ void scan1_kernel(int* __restrict__ deg, int* __restrict__ tops, int n)
{
    __shared__ int sh[256];
    int i = blockIdx.x * 256 + threadIdx.x;
    int v = (i < n) ? deg[i] : 0;
    sh[threadIdx.x] = v;
    __syncthreads();
    for (int o = 1; o < 256; o <<= 1) {
        int t = (threadIdx.x >= o) ? sh[threadIdx.x - o] : 0;
        __syncthreads();
        sh[threadIdx.x] += t;
        __syncthreads();
    }
    if (i < n) deg[i] = sh[threadIdx.x];
    if (threadIdx.x == 255) tops[blockIdx.x] = sh[255];
}

__global__ void scan2_kernel(int* __restrict__ tops, int nb)
{
    __shared__ int sh[1024];
    int v = (threadIdx.x < nb) ? tops[threadIdx.x] : 0;
    sh[threadIdx.x] = v;
    __syncthreads();
    for (int o = 1; o < 1024; o <<= 1) {
        int t = (threadIdx.x >= o) ? sh[threadIdx.x - o] : 0;
        __syncthreads();
        sh[threadIdx.x] += t;
        __syncthreads();
    }
    if (threadIdx.x < nb) tops[threadIdx.x] = sh[threadIdx.x];
}

__global__ void scan3_kernel(const int* __restrict__ part, const int* __restrict__ tops,
                             int* __restrict__ rowptr, int* __restrict__ cursor, int n)
{
    int i = blockIdx.x * 256 + threadIdx.x;
    if (i >= n) return;
    int add = (blockIdx.x > 0) ? tops[blockIdx.x - 1] : 0;
    int prev = (i > 0) ? ((threadIdx.x > 0) ? part[i - 1] + add
                                            : ((blockIdx.x > 0) ? tops[blockIdx.x - 1] : 0))
                       : 0;
    rowptr[i + 1] = part[i] + add;
    cursor[i] = prev;
    if (i == 0) rowptr[0] = 0;
}

// col entry: (src_row << 2) | edge_type
__global__ void scatter_kernel(const int* __restrict__ ti_src, const int* __restrict__ ti_dst,
                               const int* __restrict__ im_src, const int* __restrict__ im_dst,
                               const int* __restrict__ ub_src, const int* __restrict__ ub_dst,
                               const int* __restrict__ bu_src, const int* __restrict__ bu_dst,
                               int* __restrict__ cursor, int* __restrict__ col)
{
    int i = blockIdx.x * blockDim.x + threadIdx.x;
    if (i >= ETOT) return;
    int d, row, et;
    if (i < E_TI)                    { d = ti_dst[i];                 row = BASE_T + ti_src[i];                 et = 0; }
    else if (i < E_TI + E_IM)        { int e = i - E_TI;              row = BASE_G + im_src[e]; d = im_dst[e];  et = 1; }
    else if (i < E_TI + E_IM + E_UB) { int e = i - E_TI - E_IM;       row = BASE_U + ub_src[e]; d = ub_dst[e];  et = 2; }
    else                             { int e = i - E_TI - E_IM - E_UB; row = BASE_I + bu_src[e]; d = NI + bu_dst[e]; et = 3; }
    int p = atomicAdd(&cursor[d], 1);
    col[p] = (row << 2) | et;
}

// ------------------- fused edge softmax-attention (online, one pass) -------------------
__global__ __launch_bounds__(256) void f12_kernel(
    const int* __restrict__ rowptr, const int* __restrict__ rowend,
    const int* __restrict__ col,
    const unsigned int* __restrict__ krw,   // bf16x2 per uint, row stride 64
    const float* __restrict__ q_i, const float* __restrict__ q_u,
    const unsigned int* __restrict__ vrw,
    const float* __restrict__ prel,
    float* __restrict__ agg_i, float* __restrict__ agg_u)
{
    int wid = (blockIdx.x << 2) + (threadIdx.x >> 6);
    if (wid >= ND) return;
    const int l = threadIdx.x & 63;
    const int h = l >> 3;

    const float* qrow = (wid < NI) ? q_i + (size_t)wid * HIDN
                                   : q_u + (size_t)(wid - NI) * HIDN;
    float2 qv = *(const float2*)(qrow + 2 * l);
    const float pr0 = prel[h]      * 0.25f;
    const float pr1 = prel[8 + h]  * 0.25f;
    const float pr2 = prel[16 + h] * 0.25f;
    const float pr3 = prel[24 + h] * 0.25f;

    const int start = rowptr[wid], end = rowend[wid];
    float m = -3.0e38f, ax = 0.f, ay = 0.f, den = 0.f;

    int p = start;
    for (; p + 1 < end; p += 2) {
        int pk0 = col[p], pk1 = col[p + 1];
        unsigned int u0 = krw[(size_t)(pk0 >> 2) * 64 + l];
        unsigned int u1 = krw[(size_t)(pk1 >> 2) * 64 + l];
        unsigned int v0 = vrw[(size_t)(pk0 >> 2) * 64 + l];
        unsigned int v1 = vrw[(size_t)(pk1 >> 2) * 64 + l];
        float d0 = qv.x * bflo(u0) + qv.y * bfhi(u0);
        float d1 = qv.x * bflo(u1) + qv.y * bfhi(u1);
        d0 += __shfl_xor(d0, 1); d1 += __shfl_xor(d1, 1);
        d0 += __shfl_xor(d0, 2); d1 += __shfl_xor(d1, 2);
        d0 += __shfl_xor(d0, 4); d1 += __shfl_xor(d1, 4);
        int e0t = pk0 & 3, e1t = pk1 & 3;
        float f0 = (e0t & 2) ? ((e0t & 1) ? pr3 : pr2) : ((e0t & 1) ? pr1 : pr0);
        float f1 = (e1t & 2) ? ((e1t & 1) ? pr3 : pr2) : ((e1t & 1) ? pr1 : pr0);
        float a0 = d0 * f0;
        float a1 = d1 * f1;
        float mn = fmaxf(m, fmaxf(a0, a1));
        float s  = __expf(m - mn);
        float e0 = __expf(a0 - mn);
        float e1 = __expf(a1 - mn);
        ax = ax * s + e0 * bflo(v0) + e1 * bflo(v1);
        ay = ay * s + e0 * bfhi(v0) + e1 * bfhi(v1);
        den = den * s + e0 + e1;
        m = mn;
    }
    if (p < end) {
        int pk0 = col[p];
        unsigned int u0 = krw[(size_t)(pk0 >> 2) * 64 + l];
        unsigned int v0 = vrw[(size_t)(pk0 >> 2) * 64 + l];
        float d0 = qv.x * bflo(u0) + qv.y * bfhi(u0);
        d0 += __shfl_xor(d0, 1);
        d0 += __shfl_xor(d0, 2);
        d0 += __shfl_xor(d0, 4);
        int e0t = pk0 & 3;
        float f0 = (e0t & 2) ? ((e0t & 1) ? pr3 : pr2) : ((e0t & 1) ? pr1 : pr0);
        float a0 = d0 * f0;
        float mn = fmaxf(m, a0);
        float s  = __expf(m - mn);
        float e0 = __expf(a0 - mn);
        ax = ax * s + e0 * bflo(v0);
        ay = ay * s + e0 * bfhi(v0);
        den = den * s + e0;
    }

    float inv = 1.f / (den + 1e-16f);
    float* dst = (wid < NI) ? agg_i + (size_t)wid * HIDN
                            : agg_u + (size_t)(wid - NI) * HIDN;
    *(float2*)(dst + 2 * l) = make_float2(ax * inv, ay * inv);
}

extern "C" void kernel_launch(void* const* d_in, const int* in_sizes, int n_in,
                              void* d_out, int out_size, void* d_ws, size_t ws_size,
                              hipStream_t stream)
{
    const float* x_user = (const float*)d_in[0];
    const float* x_item = (const float*)d_in[1];
    const float* x_taste= (const float*)d_in[2];
    const float* x_image= (const float*)d_in[3];
    const float* Wk     = (const float*)d_in[4];
    const float* bk     = (const float*)d_in[5];
    const float* Wq     = (const float*)d_in[6];
    const float* bq     = (const float*)d_in[7];
    const float* Wv     = (const float*)d_in[8];
    const float* bv     = (const float*)d_in[9];
    const float* a_rel  = (const float*)d_in[10];
    const float* m_rel  = (const float*)d_in[11];
    const float* p_rel  = (const float*)d_in[12];
    const float* Wo     = (const float*)d_in[13];
    const float* bo     = (const float*)d_in[14];
    const float* skip   = (const float*)d_in[15];
    const int* ti_src = (const int*)d_in[16];
    const int* ti_dst = (const int*)d_in[17];
    const int* im_src = (const int*)d_in[18];
    const int* im_dst = (const int*)d_in[19];
    const int* ub_src = (const int*)d_in[20];
    const int* ub_dst = (const int*)d_in[21];
    const int* bu_src = (const int*)d_in[22];
    const int* bu_dst = (const int*)d_in[23];

    float* ws = (float*)d_ws;
    float* outp = (float*)d_out;
    (void)in_sizes; (void)n_in; (void)out_size;

    // ---- workspace layout (floats) ----
    size_t off = 0;
    auto alloc = [&](size_t n) { size_t o = off; off += n; return o; };
    const size_t o_cw   = alloc((size_t)2 * 4 * 129 * 128);   // reused as deg[] after pack
    const size_t o_pkh  = alloc((size_t)NMAT * MATSZ / 2);
    const size_t o_pkl  = alloc((size_t)NMAT * MATSZ / 2);
    const size_t o_bias = alloc((size_t)NMAT * HIDN);
    const size_t o_krb  = alloc((size_t)(NU + NI + NT + NG) * HIDN / 2);  // bf16 table
    const size_t o_vrb  = alloc((size_t)(NU + NI + NT + NG) * HIDN / 2);  // bf16 table
    const size_t o_q_i  = alloc((size_t)NI * HIDN);
    const size_t o_q_u  = alloc((size_t)NU * HIDN);
    const size_t o_agg  = alloc((size_t)(NI + NU) * HIDN);
    const size_t o_int  = alloc((size_t)(ND + 1) + ND + 1024 + ETOT);

    if (ws_size < off * sizeof(float)) return;  // clean failure instead of OOB fault

    unsigned short* krb = (unsigned short*)(ws + o_krb);
    unsigned short* vrb = (unsigned short*)(ws + o_vrb);

    short* pkh  = (short*)(ws + o_pkh);
    short* pkl  = (short*)(ws + o_pkl);
    float* bias = ws + o_bias;

    int* deg    = (int*)(ws + o_cw);        // overlays cw (dead after pack)
    int* rowptr = (int*)(ws + o_int);
    int* cursor = rowptr + (ND + 1);
    int* tops   = cursor + ND;
    int* col    = tops + 1024;

    float* agg_i = ws + o_agg;
    float* agg_u = ws + o_agg + (size_t)NI * HIDN;

    // ---- 1. combined weights + MFMA pack ----
    {
        int total = 2 * 4 * 129 * 128;
        build_cw_kernel<<<(total + 255) / 256, 256, 0, stream>>>(
            Wk, bk, Wv, bv, a_rel, m_rel, ws + o_cw);
        int ptotal = NMAT * MATSZ + NMAT * HIDN;
        pack_kernel<<<(ptotal + 255) / 256, 256, 0, stream>>>(
            ws + o_cw, Wq, bq, Wo, bo, pkh, pkl, bias);
    }

    // ---- 2. projections (B-stationary) ----
    mfma_proj_all<<<NBU + NBI + NBT + NBG, 256, 0, stream>>>(
        x_user, x_item, x_taste, x_image, pkh, pkl, bias,
        krb, vrb, ws + o_q_u, ws + o_q_i);

    // ---- 3. CSR build ----
    hipMemsetAsync(deg, 0, ND * sizeof(int), stream);
    hist_kernel<<<(ETOT + 255) / 256, 256, 0, stream>>>(ti_dst, im_dst, ub_dst, bu_dst, deg);
    const int NB1 = (ND + 255) / 256;
    scan1_kernel<<<NB1, 256, 0, stream>>>(deg, tops, ND);
    scan2_kernel<<<1, 1024, 0, stream>>>(tops, NB1);
    scan3_kernel<<<NB1, 256, 0, stream>>>(deg, tops, rowptr, cursor, ND);
    scatter_kernel<<<(ETOT + 255) / 256, 256, 0, stream>>>(
        ti_src, ti_dst, im_src, im_dst, ub_src, ub_dst, bu_src, bu_dst, cursor, col);
    // after scatter, cursor[d] == row end

    // ---- 4. fused online-softmax edge aggregation ----
    const int NBW = (ND + 3) / 4;
    f12_kernel<<<NBW, 256, 0, stream>>>(
        rowptr, cursor, col,
        (const unsigned int*)krb, ws + o_q_i, ws + o_q_u,
        (const unsigned int*)vrb, p_rel,
        agg_i, agg_u);

    // ---- 5. epilogue (B-stationary) ----
    mfma_out_all<<<NBI + NBU, 256, 0, stream>>>(
        agg_i, agg_u, pkh, pkl, bias, x_item, x_user, skip, outp);
}

// Round 12
// 337.449 us; speedup vs baseline: 1.3335x; 1.1798x over previous
//
#include <hip/hip_runtime.h>
#include <math.h>

// ---------------------------------------------------------------------------
// MultiModalFusionGAT — round 12
//   = round 11 (B-stationary MFMA proj/epilogue, online-softmax edge kernel)
//   + q stored as bf16 (-36MB total traffic)
//   + k/v proj: 2-term split-bf16 (drop ahi*Blo; below output-rounding level)
// ---------------------------------------------------------------------------

namespace {
constexpr int HIDN  = 128;
constexpr int NHEAD = 8;

constexpr int NU = 20000, NI = 50000, NT = 50000, NG = 50000;
constexpr int E_TI = 50000, E_IM = 50000, E_UB = 500000, E_BU = 500000;
constexpr int ETOT = E_TI + E_IM + E_UB + E_BU;   // 1,100,000
constexpr int ND   = NI + NU;                     // dst nodes: items then users

constexpr int BASE_U = 0;
constexpr int BASE_I = NU;
constexpr int BASE_T = NU + NI;
constexpr int BASE_G = NU + NI + NT;

constexpr int NMAT = 12;           // 0..3 k, 4..7 v, 8/9 q(user,item), 10/11 Wo(item,user)
constexpr int MATSZ = 128 * 128;
constexpr int SU = 136;            // ushort stride for hi/lo LDS planes

constexpr int NBU = (NU + 63) / 64;
constexpr int NBI = (NI + 63) / 64;
constexpr int NBT = (NT + 63) / 64;
constexpr int NBG = (NG + 63) / 64;
}

typedef __attribute__((ext_vector_type(8))) short short8v;
typedef __attribute__((ext_vector_type(4))) float f32x4;
typedef __attribute__((ext_vector_type(4))) unsigned short ushort4v;

__device__ __forceinline__ unsigned short bf16rne(float f) {
    unsigned u = __float_as_uint(f);
    unsigned r = (u + 0x7fffu + ((u >> 16) & 1u)) >> 16;
    return (unsigned short)r;
}
__device__ __forceinline__ float bf16f(unsigned short h) {
    return __uint_as_float(((unsigned)h) << 16);
}
__device__ __forceinline__ float bflo(unsigned int u) { return __uint_as_float(u << 16); }
__device__ __forceinline__ float bfhi(unsigned int u) { return __uint_as_float(u & 0xffff0000u); }

// cw layout: [which(2)][type(4)][row(129)][col(128)]; row 128 = transformed bias
__global__ void build_cw_kernel(const float* __restrict__ Wk, const float* __restrict__ bk,
                                const float* __restrict__ Wv, const float* __restrict__ bv,
                                const float* __restrict__ a_rel, const float* __restrict__ m_rel,
                                float* __restrict__ cw)
{
    const int total = 2 * 4 * 129 * 128;
    int idx = blockIdx.x * blockDim.x + threadIdx.x;
    if (idx >= total) return;
    int c     = idx & 127;
    int r     = (idx >> 7) % 129;
    int t     = ((idx >> 7) / 129) & 3;
    int which = idx / (4 * 129 * 128);
    const int et_map[4] = {2, 3, 0, 1};
    int et = et_map[t];
    const float* W = (which == 0 ? Wk : Wv) + (size_t)t * HIDN * HIDN;
    const float* b = (which == 0 ? bk : bv) + (size_t)t * HIDN;
    const float* A = (which == 0 ? a_rel : m_rel) + (size_t)et * NHEAD * 16 * 16;
    int h = c >> 4, e2 = c & 15;
    float s = 0.f;
#pragma unroll
    for (int d = 0; d < 16; ++d) {
        float w = (r == 128) ? b[h * 16 + d] : W[(size_t)r * HIDN + h * 16 + d];
        s = fmaf(w, A[h * 256 + d * 16 + e2], s);
    }
    cw[idx] = s;
}

__global__ void pack_kernel(const float* __restrict__ cw,
                            const float* __restrict__ Wq, const float* __restrict__ bq,
                            const float* __restrict__ Wo, const float* __restrict__ bo,
                            short* __restrict__ pkh, short* __restrict__ pkl,
                            float* __restrict__ bias)
{
    const int total = NMAT * MATSZ + NMAT * HIDN;
    int idx = blockIdx.x * blockDim.x + threadIdx.x;
    if (idx >= total) return;
    if (idx < NMAT * MATSZ) {
        int mat = idx >> 14;
        int rem = idx & (MATSZ - 1);
        int i    = rem & 7;
        int lane = (rem >> 3) & 63;
        int ct   = (rem >> 9) & 7;
        int ks   = rem >> 12;
        int k   = ks * 32 + ((lane >> 4) & 3) * 8 + i;
        int col = ct * 16 + (lane & 15);
        float v;
        if (mat < 8)       v = cw[(size_t)mat * 129 * 128 + (size_t)k * 128 + col];
        else if (mat < 10) v = Wq[(size_t)(mat - 8) * MATSZ + (size_t)k * 128 + col];
        else               v = Wo[(size_t)(mat - 10) * MATSZ + (size_t)k * 128 + col];
        unsigned short hb = bf16rne(v);
        float rest = v - bf16f(hb);
        pkh[idx] = (short)hb;
        pkl[idx] = (short)bf16rne(rest);
    } else {
        int b = idx - NMAT * MATSZ;
        int mat = b >> 7, col = b & 127;
        float v;
        if (mat < 8)       v = cw[(size_t)mat * 129 * 128 + (size_t)128 * 128 + col];
        else if (mat < 10) v = bq[(mat - 8) * HIDN + col];
        else               v = bo[(mat - 10) * HIDN + col];
        bias[b] = v;
    }
}

// B-stationary projections; k/v = 2-term split, q = 3-term split, all bf16 out.
__global__ __launch_bounds__(256) void mfma_proj_all(
    const float* __restrict__ xu, const float* __restrict__ xi,
    const float* __restrict__ xt, const float* __restrict__ xg,
    const short* __restrict__ pkh, const short* __restrict__ pkl,
    const float* __restrict__ bias,
    unsigned short* __restrict__ krb, unsigned short* __restrict__ vrb,
    unsigned short* __restrict__ qb_u, unsigned short* __restrict__ qb_i)
{
    int b = blockIdx.x;
    int seg, bloc;
    if (b < NBU)                  { seg = 0; bloc = b; }
    else if (b < NBU + NBI)       { seg = 1; bloc = b - NBU; }
    else if (b < NBU + NBI + NBT) { seg = 2; bloc = b - NBU - NBI; }
    else                          { seg = 3; bloc = b - NBU - NBI - NBT; }
    const float* x = (seg == 0) ? xu : (seg == 1) ? xi : (seg == 2) ? xt : xg;
    const int M     = (seg == 0) ? NU : (seg == 1) ? NI : (seg == 2) ? NT : NG;
    const int rbase = (seg == 0) ? BASE_U : (seg == 1) ? BASE_I : (seg == 2) ? BASE_T : BASE_G;
    unsigned short* qp = (seg == 0) ? qb_u : (seg == 1) ? qb_i : nullptr;

    __shared__ unsigned short hs[64 * SU];
    __shared__ unsigned short ls[64 * SU];
    const int t  = threadIdx.x;
    const int r0 = bloc * 64;
    const int rows = min(64, M - r0);

    // stage A pre-split into bf16 hi/lo planes
#pragma unroll
    for (int p = 0; p < 8; ++p) {
        int f = p * 256 + t;
        int row = f >> 5, c4 = f & 31;
        float4 v = make_float4(0.f, 0.f, 0.f, 0.f);
        if (row < rows) v = *(const float4*)(x + (size_t)(r0 + row) * HIDN + c4 * 4);
        float vv[4] = {v.x, v.y, v.z, v.w};
        ushort4v hq, lq;
#pragma unroll
        for (int i = 0; i < 4; ++i) {
            unsigned short hb = bf16rne(vv[i]);
            hq[i] = hb;
            lq[i] = bf16rne(vv[i] - bf16f(hb));
        }
        *(ushort4v*)&hs[row * SU + c4 * 4] = hq;
        *(ushort4v*)&ls[row * SU + c4 * 4] = lq;
    }
    __syncthreads();

    const int l = t & 63, w = t >> 6;
    const int kgrp = l >> 4;
    const int ct0  = 2 * w;
    const int ccol = l & 15;

    for (int mi = 0; mi < 3; ++mi) {
        if (mi == 2 && qp == nullptr) break;
        const int mat = (mi == 0) ? seg : (mi == 1) ? (4 + seg) : (8 + seg);
        const short8v* bh = (const short8v*)(pkh + (size_t)mat * MATSZ);
        const short8v* bl = (const short8v*)(pkl + (size_t)mat * MATSZ);
        const float*   bs = bias + mat * HIDN;

        short8v B1[4][2], B2[4][2];
#pragma unroll
        for (int ks = 0; ks < 4; ++ks) {
#pragma unroll
            for (int c = 0; c < 2; ++c) {
                B1[ks][c] = bh[(ks * 8 + ct0 + c) * 64 + l];
                if (mi == 2) B2[ks][c] = bl[(ks * 8 + ct0 + c) * 64 + l];
            }
        }

        const float bv0 = bs[(ct0 + 0) * 16 + ccol];
        const float bv1 = bs[(ct0 + 1) * 16 + ccol];

        for (int rt = 0; rt < 4; ++rt) {
            f32x4 a0, a1;
            a0[0]=0.f;a0[1]=0.f;a0[2]=0.f;a0[3]=0.f;
            a1[0]=0.f;a1[1]=0.f;a1[2]=0.f;a1[3]=0.f;
            const int arow = rt * 16 + ccol;
#pragma unroll
            for (int ks = 0; ks < 4; ++ks) {
                short8v ah = *(const short8v*)&hs[arow * SU + ks * 32 + kgrp * 8];
                short8v al = *(const short8v*)&ls[arow * SU + ks * 32 + kgrp * 8];
                a0 = __builtin_amdgcn_mfma_f32_16x16x32_bf16(ah, B1[ks][0], a0, 0, 0, 0);
                a1 = __builtin_amdgcn_mfma_f32_16x16x32_bf16(ah, B1[ks][1], a1, 0, 0, 0);
                a0 = __builtin_amdgcn_mfma_f32_16x16x32_bf16(al, B1[ks][0], a0, 0, 0, 0);
                a1 = __builtin_amdgcn_mfma_f32_16x16x32_bf16(al, B1[ks][1], a1, 0, 0, 0);
                if (mi == 2) {
                    a0 = __builtin_amdgcn_mfma_f32_16x16x32_bf16(ah, B2[ks][0], a0, 0, 0, 0);
                    a1 = __builtin_amdgcn_mfma_f32_16x16x32_bf16(ah, B2[ks][1], a1, 0, 0, 0);
                }
            }
            const int crow = r0 + rt * 16 + kgrp * 4;
            unsigned short* dst = (mi == 0) ? krb + (size_t)rbase * HIDN
                                : (mi == 1) ? vrb + (size_t)rbase * HIDN
                                            : qp;
#pragma unroll
            for (int j = 0; j < 4; ++j) {
                int grow = crow + j;
                if (grow < M) {
                    size_t o = (size_t)grow * HIDN;
                    dst[o + (ct0 + 0) * 16 + ccol] = bf16rne(a0[j] + bv0);
                    dst[o + (ct0 + 1) * 16 + ccol] = bf16rne(a1[j] + bv1);
                }
            }
        }
    }
}

// B-stationary epilogue (full 3-term split, fp32 out).
__global__ __launch_bounds__(256) void mfma_out_all(
    const float* __restrict__ agg_i, const float* __restrict__ agg_u,
    const short* __restrict__ pkh, const short* __restrict__ pkl,
    const float* __restrict__ bias,
    const float* __restrict__ x_item, const float* __restrict__ x_user,
    const float* __restrict__ skip_ptr,
    float* __restrict__ outp)
{
    int b = blockIdx.x;
    int seg = (b < NBI) ? 0 : 1;
    int bloc = (seg == 0) ? b : b - NBI;
    const float* agg = (seg == 0) ? agg_i : agg_u;
    const float* xin = (seg == 0) ? x_item : x_user;
    const int M = (seg == 0) ? NI : NU;
    const int mat = 10 + seg;
    float* out = (seg == 0) ? outp : outp + (size_t)NI * HIDN;

    __shared__ unsigned short hs[64 * SU];
    __shared__ unsigned short ls[64 * SU];
    const int t  = threadIdx.x;
    const int r0 = bloc * 64;
    const int rows = min(64, M - r0);

#pragma unroll
    for (int p = 0; p < 8; ++p) {
        int f = p * 256 + t;
        int row = f >> 5, c4 = f & 31;
        float4 v = make_float4(0.f, 0.f, 0.f, 0.f);
        if (row < rows) v = *(const float4*)(agg + (size_t)(r0 + row) * HIDN + c4 * 4);
        float vv[4] = {v.x, v.y, v.z, v.w};
        ushort4v hq, lq;
#pragma unroll
        for (int i = 0; i < 4; ++i) {
            float g = 0.5f * vv[i] * (1.0f + erff(vv[i] * 0.70710678118654752440f));
            unsigned short hb = bf16rne(g);
            hq[i] = hb;
            lq[i] = bf16rne(g - bf16f(hb));
        }
        *(ushort4v*)&hs[row * SU + c4 * 4] = hq;
        *(ushort4v*)&ls[row * SU + c4 * 4] = lq;
    }
    __syncthreads();

    const int l = t & 63, w = t >> 6;
    const int kgrp = l >> 4;
    const int ct0  = 2 * w;
    const int ccol = l & 15;

    const short8v* bh = (const short8v*)(pkh + (size_t)mat * MATSZ);
    const short8v* bl = (const short8v*)(pkl + (size_t)mat * MATSZ);
    const float*   bs = bias + mat * HIDN;

    short8v B1[4][2], B2[4][2];
#pragma unroll
    for (int ks = 0; ks < 4; ++ks) {
#pragma unroll
        for (int c = 0; c < 2; ++c) {
            B1[ks][c] = bh[(ks * 8 + ct0 + c) * 64 + l];
            B2[ks][c] = bl[(ks * 8 + ct0 + c) * 64 + l];
        }
    }

    const float gate = 1.f / (1.f + expf(-skip_ptr[seg]));
    const float og = 1.f - gate;
    const float bv0 = bs[(ct0 + 0) * 16 + ccol];
    const float bv1 = bs[(ct0 + 1) * 16 + ccol];

    for (int rt = 0; rt < 4; ++rt) {
        f32x4 a0, a1;
        a0[0]=0.f;a0[1]=0.f;a0[2]=0.f;a0[3]=0.f;
        a1[0]=0.f;a1[1]=0.f;a1[2]=0.f;a1[3]=0.f;
        const int arow = rt * 16 + ccol;
#pragma unroll
        for (int ks = 0; ks < 4; ++ks) {
            short8v ah = *(const short8v*)&hs[arow * SU + ks * 32 + kgrp * 8];
            short8v al = *(const short8v*)&ls[arow * SU + ks * 32 + kgrp * 8];
            a0 = __builtin_amdgcn_mfma_f32_16x16x32_bf16(ah, B1[ks][0], a0, 0, 0, 0);
            a1 = __builtin_amdgcn_mfma_f32_16x16x32_bf16(ah, B1[ks][1], a1, 0, 0, 0);
            a0 = __builtin_amdgcn_mfma_f32_16x16x32_bf16(al, B1[ks][0], a0, 0, 0, 0);
            a1 = __builtin_amdgcn_mfma_f32_16x16x32_bf16(al, B1[ks][1], a1, 0, 0, 0);
            a0 = __builtin_amdgcn_mfma_f32_16x16x32_bf16(ah, B2[ks][0], a0, 0, 0, 0);
            a1 = __builtin_amdgcn_mfma_f32_16x16x32_bf16(ah, B2[ks][1], a1, 0, 0, 0);
        }
        const int crow = r0 + rt * 16 + kgrp * 4;
#pragma unroll
        for (int j = 0; j < 4; ++j) {
            int grow = crow + j;
            if (grow < M) {
                size_t o = (size_t)grow * HIDN;
                size_t o0 = o + (ct0 + 0) * 16 + ccol;
                size_t o1 = o + (ct0 + 1) * 16 + ccol;
                out[o0] = gate * (a0[j] + bv0) + og * xin[o0];
                out[o1] = gate * (a1[j] + bv1) + og * xin[o1];
            }
        }
    }
}

// ----------------------- CSR construction -----------------------

__global__ void hist_kernel(const int* __restrict__ ti_dst, const int* __restrict__ im_dst,
                            const int* __restrict__ ub_dst, const int* __restrict__ bu_dst,
                            int* __restrict__ deg)
{
    int i = blockIdx.x * blockDim.x + threadIdx.x;
    if (i >= ETOT) return;
    int d;
    if (i < E_TI)                     d = ti_dst[i];
    else if (i < E_TI + E_IM)         d = im_dst[i - E_TI];
    else if (i < E_TI + E_IM + E_UB)  d = ub_dst[i - E_TI - E_IM];
    else                              d = NI + bu_dst[i - E_TI - E_IM - E_UB];
    atomicAdd(&deg[d], 1);
}

__global__ void scan1_kernel(int* __restrict__ deg, int* __restrict__ tops, int n)
{
    __shared__ int sh[256];
    int i = blockIdx.x * 256 + threadIdx.x;
    int v = (i < n) ? deg[i] : 0;
    sh[threadIdx.x] = v;
    __syncthreads();
    for (int o = 1; o < 256; o <<= 1) {
        int t = (threadIdx.x >= o) ? sh[threadIdx.x - o] : 0;
        __syncthreads();
        sh[threadIdx.x] += t;
        __syncthreads();
    }
    if (i < n) deg[i] = sh[threadIdx.x];
    if (threadIdx.x == 255) tops[blockIdx.x] = sh[255];
}

__global__ void scan2_kernel(int* __restrict__ tops, int nb)
{
    __shared__ int sh[1024];
    int v = (threadIdx.x < nb) ? tops[threadIdx.x] : 0;
    sh[threadIdx.x] = v;
    __syncthreads();
    for (int o = 1; o < 1024; o <<= 1) {
        int t = (threadIdx.x >= o) ? sh[threadIdx.x - o] : 0;
        __syncthreads();
        sh[threadIdx.x] += t;
        __syncthreads();
    }
    if (threadIdx.x < nb) tops[threadIdx.x] = sh[threadIdx.x];
}

__global__ void scan3_kernel(const int* __restrict__ part, const int* __restrict__ tops,
                             int* __restrict__ rowptr, int* __restrict__ cursor, int n)
{
    int i = blockIdx.x * 256 + threadIdx.x;
    if (i >= n) return;
    int add = (blockIdx.x > 0) ? tops[blockIdx.x - 1] : 0;
    int prev = (i > 0) ? ((threadIdx.x > 0) ? part[i - 1] + add
                                            : ((blockIdx.x > 0) ? tops[blockIdx.x - 1] : 0))
                       : 0;
    rowptr[i + 1] = part[i] + add;
    cursor[i] = prev;
    if (i == 0) rowptr[0] = 0;
}

// col entry: (src_row << 2) | edge_type
__global__ void scatter_kernel(const int* __restrict__ ti_src, const int* __restrict__ ti_dst,
                               const int* __restrict__ im_src, const int* __restrict__ im_dst,
                               const int* __restrict__ ub_src, const int* __restrict__ ub_dst,
                               const int* __restrict__ bu_src, const int* __restrict__ bu_dst,
                               int* __restrict__ cursor, int* __restrict__ col)
{
    int i = blockIdx.x * blockDim.x + threadIdx.x;
    if (i >= ETOT) return;
    int d, row, et;
    if (i < E_TI)                    { d = ti_dst[i];                 row = BASE_T + ti_src[i];                 et = 0; }
    else if (i < E_TI + E_IM)        { int e = i - E_TI;              row = BASE_G + im_src[e]; d = im_dst[e];  et = 1; }
    else if (i < E_TI + E_IM + E_UB) { int e = i - E_TI - E_IM;       row = BASE_U + ub_src[e]; d = ub_dst[e];  et = 2; }
    else                             { int e = i - E_TI - E_IM - E_UB; row = BASE_I + bu_src[e]; d = NI + bu_dst[e]; et = 3; }
    int p = atomicAdd(&cursor[d], 1);
    col[p] = (row << 2) | et;
}

// ------------------- fused edge softmax-attention (online, one pass) -------------------
__global__ __launch_bounds__(256) void f12_kernel(
    const int* __restrict__ rowptr, const int* __restrict__ rowend,
    const int* __restrict__ col,
    const unsigned int* __restrict__ krw,   // bf16x2 per uint, row stride 64
    const unsigned int* __restrict__ qb_i, const unsigned int* __restrict__ qb_u,
    const unsigned int* __restrict__ vrw,
    const float* __restrict__ prel,
    float* __restrict__ agg_i, float* __restrict__ agg_u)
{
    int wid = (blockIdx.x << 2) + (threadIdx.x >> 6);
    if (wid >= ND) return;
    const int l = threadIdx.x & 63;
    const int h = l >> 3;

    unsigned int qu = (wid < NI) ? qb_i[(size_t)wid * 64 + l]
                                 : qb_u[(size_t)(wid - NI) * 64 + l];
    float2 qv = make_float2(bflo(qu), bfhi(qu));
    const float pr0 = prel[h]      * 0.25f;
    const float pr1 = prel[8 + h]  * 0.25f;
    const float pr2 = prel[16 + h] * 0.25f;
    const float pr3 = prel[24 + h] * 0.25f;

    const int start = rowptr[wid], end = rowend[wid];
    float m = -3.0e38f, ax = 0.f, ay = 0.f, den = 0.f;

    int p = start;
    for (; p + 1 < end; p += 2) {
        int pk0 = col[p], pk1 = col[p + 1];
        unsigned int u0 = krw[(size_t)(pk0 >> 2) * 64 + l];
        unsigned int u1 = krw[(size_t)(pk1 >> 2) * 64 + l];
        unsigned int v0 = vrw[(size_t)(pk0 >> 2) * 64 + l];
        unsigned int v1 = vrw[(size_t)(pk1 >> 2) * 64 + l];
        float d0 = qv.x * bflo(u0) + qv.y * bfhi(u0);
        float d1 = qv.x * bflo(u1) + qv.y * bfhi(u1);
        d0 += __shfl_xor(d0, 1); d1 += __shfl_xor(d1, 1);
        d0 += __shfl_xor(d0, 2); d1 += __shfl_xor(d1, 2);
        d0 += __shfl_xor(d0, 4); d1 += __shfl_xor(d1, 4);
        int e0t = pk0 & 3, e1t = pk1 & 3;
        float f0 = (e0t & 2) ? ((e0t & 1) ? pr3 : pr2) : ((e0t & 1) ? pr1 : pr0);
        float f1 = (e1t & 2) ? ((e1t & 1) ? pr3 : pr2) : ((e1t & 1) ? pr1 : pr0);
        float a0 = d0 * f0;
        float a1 = d1 * f1;
        float mn = fmaxf(m, fmaxf(a0, a1));
        float s  = __expf(m - mn);
        float e0 = __expf(a0 - mn);
        float e1 = __expf(a1 - mn);
        ax = ax * s + e0 * bflo(v0) + e1 * bflo(v1);
        ay = ay * s + e0 * bfhi(v0) + e1 * bfhi(v1);
        den = den * s + e0 + e1;
        m = mn;
    }
    if (p < end) {
        int pk0 = col[p];
        unsigned int u0 = krw[(size_t)(pk0 >> 2) * 64 + l];
        unsigned int v0 = vrw[(size_t)(pk0 >> 2) * 64 + l];
        float d0 = qv.x * bflo(u0) + qv.y * bfhi(u0);
        d0 += __shfl_xor(d0, 1);
        d0 += __shfl_xor(d0, 2);
        d0 += __shfl_xor(d0, 4);
        int e0t = pk0 & 3;
        float f0 = (e0t & 2) ? ((e0t & 1) ? pr3 : pr2) : ((e0t & 1) ? pr1 : pr0);
        float a0 = d0 * f0;
        float mn = fmaxf(m, a0);
        float s  = __expf(m - mn);
        float e0 = __expf(a0 - mn);
        ax = ax * s + e0 * bflo(v0);
        ay = ay * s + e0 * bfhi(v0);
        den = den * s + e0;
    }

    float inv = 1.f / (den + 1e-16f);
    float* dst = (wid < NI) ? agg_i + (size_t)wid * HIDN
                            : agg_u + (size_t)(wid - NI) * HIDN;
    *(float2*)(dst + 2 * l) = make_float2(ax * inv, ay * inv);
}

extern "C" void kernel_launch(void* const* d_in, const int* in_sizes, int n_in,
                              void* d_out, int out_size, void* d_ws, size_t ws_size,
                              hipStream_t stream)
{
    const float* x_user = (const float*)d_in[0];
    const float* x_item = (const float*)d_in[1];
    const float* x_taste= (const float*)d_in[2];
    const float* x_image= (const float*)d_in[3];
    const float* Wk     = (const float*)d_in[4];
    const float* bk     = (const float*)d_in[5];
    const float* Wq     = (const float*)d_in[6];
    const float* bq     = (const float*)d_in[7];
    const float* Wv     = (const float*)d_in[8];
    const float* bv     = (const float*)d_in[9];
    const float* a_rel  = (const float*)d_in[10];
    const float* m_rel  = (const float*)d_in[11];
    const float* p_rel  = (const float*)d_in[12];
    const float* Wo     = (const float*)d_in[13];
    const float* bo     = (const float*)d_in[14];
    const float* skip   = (const float*)d_in[15];
    const int* ti_src = (const int*)d_in[16];
    const int* ti_dst = (const int*)d_in[17];
    const int* im_src = (const int*)d_in[18];
    const int* im_dst = (const int*)d_in[19];
    const int* ub_src = (const int*)d_in[20];
    const int* ub_dst = (const int*)d_in[21];
    const int* bu_src = (const int*)d_in[22];
    const int* bu_dst = (const int*)d_in[23];

    float* ws = (float*)d_ws;
    float* outp = (float*)d_out;
    (void)in_sizes; (void)n_in; (void)out_size;

    // ---- workspace layout (floats) ----
    size_t off = 0;
    auto alloc = [&](size_t n) { size_t o = off; off += n; return o; };
    const size_t o_cw   = alloc((size_t)2 * 4 * 129 * 128);   // reused as deg[] after pack
    const size_t o_pkh  = alloc((size_t)NMAT * MATSZ / 2);
    const size_t o_pkl  = alloc((size_t)NMAT * MATSZ / 2);
    const size_t o_bias = alloc((size_t)NMAT * HIDN);
    const size_t o_krb  = alloc((size_t)(NU + NI + NT + NG) * HIDN / 2);  // bf16
    const size_t o_vrb  = alloc((size_t)(NU + NI + NT + NG) * HIDN / 2);  // bf16
    const size_t o_q_i  = alloc((size_t)NI * HIDN / 2);                   // bf16
    const size_t o_q_u  = alloc((size_t)NU * HIDN / 2);                   // bf16
    const size_t o_agg  = alloc((size_t)(NI + NU) * HIDN);
    const size_t o_int  = alloc((size_t)(ND + 1) + ND + 1024 + ETOT);

    if (ws_size < off * sizeof(float)) return;  // clean failure instead of OOB fault

    unsigned short* krb  = (unsigned short*)(ws + o_krb);
    unsigned short* vrb  = (unsigned short*)(ws + o_vrb);
    unsigned short* qb_i = (unsigned short*)(ws + o_q_i);
    unsigned short* qb_u = (unsigned short*)(ws + o_q_u);

    short* pkh  = (short*)(ws + o_pkh);
    short* pkl  = (short*)(ws + o_pkl);
    float* bias = ws + o_bias;

    int* deg    = (int*)(ws + o_cw);        // overlays cw (dead after pack)
    int* rowptr = (int*)(ws + o_int);
    int* cursor = rowptr + (ND + 1);
    int* tops   = cursor + ND;
    int* col    = tops + 1024;

    float* agg_i = ws + o_agg;
    float* agg_u = ws + o_agg + (size_t)NI * HIDN;

    // ---- 1. combined weights + MFMA pack ----
    {
        int total = 2 * 4 * 129 * 128;
        build_cw_kernel<<<(total + 255) / 256, 256, 0, stream>>>(
            Wk, bk, Wv, bv, a_rel, m_rel, ws + o_cw);
        int ptotal = NMAT * MATSZ + NMAT * HIDN;
        pack_kernel<<<(ptotal + 255) / 256, 256, 0, stream>>>(
            ws + o_cw, Wq, bq, Wo, bo, pkh, pkl, bias);
    }

    // ---- 2. projections (B-stationary, bf16 outputs) ----
    mfma_proj_all<<<NBU + NBI + NBT + NBG, 256, 0, stream>>>(
        x_user, x_item, x_taste, x_image, pkh, pkl, bias,
        krb, vrb, qb_u, qb_i);

    // ---- 3. CSR build ----
    hipMemsetAsync(deg, 0, ND * sizeof(int), stream);
    hist_kernel<<<(ETOT + 255) / 256, 256, 0, stream>>>(ti_dst, im_dst, ub_dst, bu_dst, deg);
    const int NB1 = (ND + 255) / 256;
    scan1_kernel<<<NB1, 256, 0, stream>>>(deg, tops, ND);
    scan2_kernel<<<1, 1024, 0, stream>>>(tops, NB1);
    scan3_kernel<<<NB1, 256, 0, stream>>>(deg, tops, rowptr, cursor, ND);
    scatter_kernel<<<(ETOT + 255) / 256, 256, 0, stream>>>(
        ti_src, ti_dst, im_src, im_dst, ub_src, ub_dst, bu_src, bu_dst, cursor, col);
    // after scatter, cursor[d] == row end

    // ---- 4. fused online-softmax edge aggregation ----
    const int NBW = (ND + 3) / 4;
    f12_kernel<<<NBW, 256, 0, stream>>>(
        rowptr, cursor, col,
        (const unsigned int*)krb, (const unsigned int*)qb_i, (const unsigned int*)qb_u,
        (const unsigned int*)vrb, p_rel,
        agg_i, agg_u);

    // ---- 5. epilogue (B-stationary) ----
    mfma_out_all<<<NBI + NBU, 256, 0, stream>>>(
        agg_i, agg_u, pkh, pkl, bias, x_item, x_user, skip, outp);
}

// Round 13
// 328.371 us; speedup vs baseline: 1.3704x; 1.0276x over previous
//
#include <hip/hip_runtime.h>
#include <math.h>

// ---------------------------------------------------------------------------
// MultiModalFusionGAT — round 13
//   = round 12 (B-stationary MFMA proj/epilogue, bf16 tables, online softmax)
//   + p_rel*0.25 folded into combined k-weights (edge type determined by
//     source node type) -> f12 inner loop has no et select; col = plain row
//   + f12 edge loop unrolled x4 (8 gathers in flight)
// ---------------------------------------------------------------------------

namespace {
constexpr int HIDN  = 128;
constexpr int NHEAD = 8;

constexpr int NU = 20000, NI = 50000, NT = 50000, NG = 50000;
constexpr int E_TI = 50000, E_IM = 50000, E_UB = 500000, E_BU = 500000;
constexpr int ETOT = E_TI + E_IM + E_UB + E_BU;   // 1,100,000
constexpr int ND   = NI + NU;                     // dst nodes: items then users

constexpr int BASE_U = 0;
constexpr int BASE_I = NU;
constexpr int BASE_T = NU + NI;
constexpr int BASE_G = NU + NI + NT;

constexpr int NMAT = 12;           // 0..3 k, 4..7 v, 8/9 q(user,item), 10/11 Wo(item,user)
constexpr int MATSZ = 128 * 128;
constexpr int SU = 136;            // ushort stride for hi/lo LDS planes

constexpr int NBU = (NU + 63) / 64;
constexpr int NBI = (NI + 63) / 64;
constexpr int NBT = (NT + 63) / 64;
constexpr int NBG = (NG + 63) / 64;
}

typedef __attribute__((ext_vector_type(8))) short short8v;
typedef __attribute__((ext_vector_type(4))) float f32x4;
typedef __attribute__((ext_vector_type(4))) unsigned short ushort4v;

__device__ __forceinline__ unsigned short bf16rne(float f) {
    unsigned u = __float_as_uint(f);
    unsigned r = (u + 0x7fffu + ((u >> 16) & 1u)) >> 16;
    return (unsigned short)r;
}
__device__ __forceinline__ float bf16f(unsigned short h) {
    return __uint_as_float(((unsigned)h) << 16);
}
__device__ __forceinline__ float bflo(unsigned int u) { return __uint_as_float(u << 16); }
__device__ __forceinline__ float bfhi(unsigned int u) { return __uint_as_float(u & 0xffff0000u); }

// cw layout: [which(2)][type(4)][row(129)][col(128)]; row 128 = transformed bias
// k-side (which==0) additionally scaled by p_rel[et][h] * 0.25 (folded alpha scale)
__global__ void build_cw_kernel(const float* __restrict__ Wk, const float* __restrict__ bk,
                                const float* __restrict__ Wv, const float* __restrict__ bv,
                                const float* __restrict__ a_rel, const float* __restrict__ m_rel,
                                const float* __restrict__ p_rel,
                                float* __restrict__ cw)
{
    const int total = 2 * 4 * 129 * 128;
    int idx = blockIdx.x * blockDim.x + threadIdx.x;
    if (idx >= total) return;
    int c     = idx & 127;
    int r     = (idx >> 7) % 129;
    int t     = ((idx >> 7) / 129) & 3;
    int which = idx / (4 * 129 * 128);
    const int et_map[4] = {2, 3, 0, 1};   // node type -> its (unique) edge type
    int et = et_map[t];
    const float* W = (which == 0 ? Wk : Wv) + (size_t)t * HIDN * HIDN;
    const float* b = (which == 0 ? bk : bv) + (size_t)t * HIDN;
    const float* A = (which == 0 ? a_rel : m_rel) + (size_t)et * NHEAD * 16 * 16;
    int h = c >> 4, e2 = c & 15;
    float s = 0.f;
#pragma unroll
    for (int d = 0; d < 16; ++d) {
        float w = (r == 128) ? b[h * 16 + d] : W[(size_t)r * HIDN + h * 16 + d];
        s = fmaf(w, A[h * 256 + d * 16 + e2], s);
    }
    if (which == 0) s *= p_rel[et * NHEAD + h] * 0.25f;
    cw[idx] = s;
}

__global__ void pack_kernel(const float* __restrict__ cw,
                            const float* __restrict__ Wq, const float* __restrict__ bq,
                            const float* __restrict__ Wo, const float* __restrict__ bo,
                            short* __restrict__ pkh, short* __restrict__ pkl,
                            float* __restrict__ bias)
{
    const int total = NMAT * MATSZ + NMAT * HIDN;
    int idx = blockIdx.x * blockDim.x + threadIdx.x;
    if (idx >= total) return;
    if (idx < NMAT * MATSZ) {
        int mat = idx >> 14;
        int rem = idx & (MATSZ - 1);
        int i    = rem & 7;
        int lane = (rem >> 3) & 63;
        int ct   = (rem >> 9) & 7;
        int ks   = rem >> 12;
        int k   = ks * 32 + ((lane >> 4) & 3) * 8 + i;
        int col = ct * 16 + (lane & 15);
        float v;
        if (mat < 8)       v = cw[(size_t)mat * 129 * 128 + (size_t)k * 128 + col];
        else if (mat < 10) v = Wq[(size_t)(mat - 8) * MATSZ + (size_t)k * 128 + col];
        else               v = Wo[(size_t)(mat - 10) * MATSZ + (size_t)k * 128 + col];
        unsigned short hb = bf16rne(v);
        float rest = v - bf16f(hb);
        pkh[idx] = (short)hb;
        pkl[idx] = (short)bf16rne(rest);
    } else {
        int b = idx - NMAT * MATSZ;
        int mat = b >> 7, col = b & 127;
        float v;
        if (mat < 8)       v = cw[(size_t)mat * 129 * 128 + (size_t)128 * 128 + col];
        else if (mat < 10) v = bq[(mat - 8) * HIDN + col];
        else               v = bo[(mat - 10) * HIDN + col];
        bias[b] = v;
    }
}

// B-stationary projections; k/v = 2-term split, q = 3-term split, all bf16 out.
__global__ __launch_bounds__(256) void mfma_proj_all(
    const float* __restrict__ xu, const float* __restrict__ xi,
    const float* __restrict__ xt, const float* __restrict__ xg,
    const short* __restrict__ pkh, const short* __restrict__ pkl,
    const float* __restrict__ bias,
    unsigned short* __restrict__ krb, unsigned short* __restrict__ vrb,
    unsigned short* __restrict__ qb_u, unsigned short* __restrict__ qb_i)
{
    int b = blockIdx.x;
    int seg, bloc;
    if (b < NBU)                  { seg = 0; bloc = b; }
    else if (b < NBU + NBI)       { seg = 1; bloc = b - NBU; }
    else if (b < NBU + NBI + NBT) { seg = 2; bloc = b - NBU - NBI; }
    else                          { seg = 3; bloc = b - NBU - NBI - NBT; }
    const float* x = (seg == 0) ? xu : (seg == 1) ? xi : (seg == 2) ? xt : xg;
    const int M     = (seg == 0) ? NU : (seg == 1) ? NI : (seg == 2) ? NT : NG;
    const int rbase = (seg == 0) ? BASE_U : (seg == 1) ? BASE_I : (seg == 2) ? BASE_T : BASE_G;
    unsigned short* qp = (seg == 0) ? qb_u : (seg == 1) ? qb_i : nullptr;

    __shared__ unsigned short hs[64 * SU];
    __shared__ unsigned short ls[64 * SU];
    const int t  = threadIdx.x;
    const int r0 = bloc * 64;
    const int rows = min(64, M - r0);

#pragma unroll
    for (int p = 0; p < 8; ++p) {
        int f = p * 256 + t;
        int row = f >> 5, c4 = f & 31;
        float4 v = make_float4(0.f, 0.f, 0.f, 0.f);
        if (row < rows) v = *(const float4*)(x + (size_t)(r0 + row) * HIDN + c4 * 4);
        float vv[4] = {v.x, v.y, v.z, v.w};
        ushort4v hq, lq;
#pragma unroll
        for (int i = 0; i < 4; ++i) {
            unsigned short hb = bf16rne(vv[i]);
            hq[i] = hb;
            lq[i] = bf16rne(vv[i] - bf16f(hb));
        }
        *(ushort4v*)&hs[row * SU + c4 * 4] = hq;
        *(ushort4v*)&ls[row * SU + c4 * 4] = lq;
    }
    __syncthreads();

    const int l = t & 63, w = t >> 6;
    const int kgrp = l >> 4;
    const int ct0  = 2 * w;
    const int ccol = l & 15;

    for (int mi = 0; mi < 3; ++mi) {
        if (mi == 2 && qp == nullptr) break;
        const int mat = (mi == 0) ? seg : (mi == 1) ? (4 + seg) : (8 + seg);
        const short8v* bh = (const short8v*)(pkh + (size_t)mat * MATSZ);
        const short8v* bl = (const short8v*)(pkl + (size_t)mat * MATSZ);
        const float*   bs = bias + mat * HIDN;

        short8v B1[4][2], B2[4][2];
#pragma unroll
        for (int ks = 0; ks < 4; ++ks) {
#pragma unroll
            for (int c = 0; c < 2; ++c) {
                B1[ks][c] = bh[(ks * 8 + ct0 + c) * 64 + l];
                if (mi == 2) B2[ks][c] = bl[(ks * 8 + ct0 + c) * 64 + l];
            }
        }

        const float bv0 = bs[(ct0 + 0) * 16 + ccol];
        const float bv1 = bs[(ct0 + 1) * 16 + ccol];

        for (int rt = 0; rt < 4; ++rt) {
            f32x4 a0, a1;
            a0[0]=0.f;a0[1]=0.f;a0[2]=0.f;a0[3]=0.f;
            a1[0]=0.f;a1[1]=0.f;a1[2]=0.f;a1[3]=0.f;
            const int arow = rt * 16 + ccol;
#pragma unroll
            for (int ks = 0; ks < 4; ++ks) {
                short8v ah = *(const short8v*)&hs[arow * SU + ks * 32 + kgrp * 8];
                short8v al = *(const short8v*)&ls[arow * SU + ks * 32 + kgrp * 8];
                a0 = __builtin_amdgcn_mfma_f32_16x16x32_bf16(ah, B1[ks][0], a0, 0, 0, 0);
                a1 = __builtin_amdgcn_mfma_f32_16x16x32_bf16(ah, B1[ks][1], a1, 0, 0, 0);
                a0 = __builtin_amdgcn_mfma_f32_16x16x32_bf16(al, B1[ks][0], a0, 0, 0, 0);
                a1 = __builtin_amdgcn_mfma_f32_16x16x32_bf16(al, B1[ks][1], a1, 0, 0, 0);
                if (mi == 2) {
                    a0 = __builtin_amdgcn_mfma_f32_16x16x32_bf16(ah, B2[ks][0], a0, 0, 0, 0);
                    a1 = __builtin_amdgcn_mfma_f32_16x16x32_bf16(ah, B2[ks][1], a1, 0, 0, 0);
                }
            }
            const int crow = r0 + rt * 16 + kgrp * 4;
            unsigned short* dst = (mi == 0) ? krb + (size_t)rbase * HIDN
                                : (mi == 1) ? vrb + (size_t)rbase * HIDN
                                            : qp;
#pragma unroll
            for (int j = 0; j < 4; ++j) {
                int grow = crow + j;
                if (grow < M) {
                    size_t o = (size_t)grow * HIDN;
                    dst[o + (ct0 + 0) * 16 + ccol] = bf16rne(a0[j] + bv0);
                    dst[o + (ct0 + 1) * 16 + ccol] = bf16rne(a1[j] + bv1);
                }
            }
        }
    }
}

// B-stationary epilogue (full 3-term split, fp32 out).
__global__ __launch_bounds__(256) void mfma_out_all(
    const float* __restrict__ agg_i, const float* __restrict__ agg_u,
    const short* __restrict__ pkh, const short* __restrict__ pkl,
    const float* __restrict__ bias,
    const float* __restrict__ x_item, const float* __restrict__ x_user,
    const float* __restrict__ skip_ptr,
    float* __restrict__ outp)
{
    int b = blockIdx.x;
    int seg = (b < NBI) ? 0 : 1;
    int bloc = (seg == 0) ? b : b - NBI;
    const float* agg = (seg == 0) ? agg_i : agg_u;
    const float* xin = (seg == 0) ? x_item : x_user;
    const int M = (seg == 0) ? NI : NU;
    const int mat = 10 + seg;
    float* out = (seg == 0) ? outp : outp + (size_t)NI * HIDN;

    __shared__ unsigned short hs[64 * SU];
    __shared__ unsigned short ls[64 * SU];
    const int t  = threadIdx.x;
    const int r0 = bloc * 64;
    const int rows = min(64, M - r0);

#pragma unroll
    for (int p = 0; p < 8; ++p) {
        int f = p * 256 + t;
        int row = f >> 5, c4 = f & 31;
        float4 v = make_float4(0.f, 0.f, 0.f, 0.f);
        if (row < rows) v = *(const float4*)(agg + (size_t)(r0 + row) * HIDN + c4 * 4);
        float vv[4] = {v.x, v.y, v.z, v.w};
        ushort4v hq, lq;
#pragma unroll
        for (int i = 0; i < 4; ++i) {
            float g = 0.5f * vv[i] * (1.0f + erff(vv[i] * 0.70710678118654752440f));
            unsigned short hb = bf16rne(g);
            hq[i] = hb;
            lq[i] = bf16rne(g - bf16f(hb));
        }
        *(ushort4v*)&hs[row * SU + c4 * 4] = hq;
        *(ushort4v*)&ls[row * SU + c4 * 4] = lq;
    }
    __syncthreads();

    const int l = t & 63, w = t >> 6;
    const int kgrp = l >> 4;
    const int ct0  = 2 * w;
    const int ccol = l & 15;

    const short8v* bh = (const short8v*)(pkh + (size_t)mat * MATSZ);
    const short8v* bl = (const short8v*)(pkl + (size_t)mat * MATSZ);
    const float*   bs = bias + mat * HIDN;

    short8v B1[4][2], B2[4][2];
#pragma unroll
    for (int ks = 0; ks < 4; ++ks) {
#pragma unroll
        for (int c = 0; c < 2; ++c) {
            B1[ks][c] = bh[(ks * 8 + ct0 + c) * 64 + l];
            B2[ks][c] = bl[(ks * 8 + ct0 + c) * 64 + l];
        }
    }

    const float gate = 1.f / (1.f + expf(-skip_ptr[seg]));
    const float og = 1.f - gate;
    const float bv0 = bs[(ct0 + 0) * 16 + ccol];
    const float bv1 = bs[(ct0 + 1) * 16 + ccol];

    for (int rt = 0; rt < 4; ++rt) {
        f32x4 a0, a1;
        a0[0]=0.f;a0[1]=0.f;a0[2]=0.f;a0[3]=0.f;
        a1[0]=0.f;a1[1]=0.f;a1[2]=0.f;a1[3]=0.f;
        const int arow = rt * 16 + ccol;
#pragma unroll
        for (int ks = 0; ks < 4; ++ks) {
            short8v ah = *(const short8v*)&hs[arow * SU + ks * 32 + kgrp * 8];
            short8v al = *(const short8v*)&ls[arow * SU + ks * 32 + kgrp * 8];
            a0 = __builtin_amdgcn_mfma_f32_16x16x32_bf16(ah, B1[ks][0], a0, 0, 0, 0);
            a1 = __builtin_amdgcn_mfma_f32_16x16x32_bf16(ah, B1[ks][1], a1, 0, 0, 0);
            a0 = __builtin_amdgcn_mfma_f32_16x16x32_bf16(al, B1[ks][0], a0, 0, 0, 0);
            a1 = __builtin_amdgcn_mfma_f32_16x16x32_bf16(al, B1[ks][1], a1, 0, 0, 0);
            a0 = __builtin_amdgcn_mfma_f32_16x16x32_bf16(ah, B2[ks][0], a0, 0, 0, 0);
            a1 = __builtin_amdgcn_mfma_f32_16x16x32_bf16(ah, B2[ks][1], a1, 0, 0, 0);
        }
        const int crow = r0 + rt * 16 + kgrp * 4;
#pragma unroll
        for (int j = 0; j < 4; ++j) {
            int grow = crow + j;
            if (grow < M) {
                size_t o = (size_t)grow * HIDN;
                size_t o0 = o + (ct0 + 0) * 16 + ccol;
                size_t o1 = o + (ct0 + 1) * 16 + ccol;
                out[o0] = gate * (a0[j] + bv0) + og * xin[o0];
                out[o1] = gate * (a1[j] + bv1) + og * xin[o1];
            }
        }
    }
}

// ----------------------- CSR construction -----------------------

__global__ void hist_kernel(const int* __restrict__ ti_dst, const int* __restrict__ im_dst,
                            const int* __restrict__ ub_dst, const int* __restrict__ bu_dst,
                            int* __restrict__ deg)
{
    int i = blockIdx.x * blockDim.x + threadIdx.x;
    if (i >= ETOT) return;
    int d;
    if (i < E_TI)                     d = ti_dst[i];
    else if (i < E_TI + E_IM)         d = im_dst[i - E_TI];
    else if (i < E_TI + E_IM + E_UB)  d = ub_dst[i - E_TI - E_IM];
    else                              d = NI + bu_dst[i - E_TI - E_IM - E_UB];
    atomicAdd(&deg[d], 1);
}

__global__ void scan1_kernel(int* __restrict__ deg, int* __restrict__ tops, int n)
{
    __shared__ int sh[256];
    int i = blockIdx.x * 256 + threadIdx.x;
    int v = (i < n) ? deg[i] : 0;
    sh[threadIdx.x] = v;
    __syncthreads();
    for (int o = 1; o < 256; o <<= 1) {
        int t = (threadIdx.x >= o) ? sh[threadIdx.x - o] : 0;
        __syncthreads();
        sh[threadIdx.x] += t;
        __syncthreads();
    }
    if (i < n) deg[i] = sh[threadIdx.x];
    if (threadIdx.x == 255) tops[blockIdx.x] = sh[255];
}

__global__ void scan2_kernel(int* __restrict__ tops, int nb)
{
    __shared__ int sh[1024];
    int v = (threadIdx.x < nb) ? tops[threadIdx.x] : 0;
    sh[threadIdx.x] = v;
    __syncthreads();
    for (int o = 1; o < 1024; o <<= 1) {
        int t = (threadIdx.x >= o) ? sh[threadIdx.x - o] : 0;
        __syncthreads();
        sh[threadIdx.x] += t;
        __syncthreads();
    }
    if (threadIdx.x < nb) tops[threadIdx.x] = sh[threadIdx.x];
}

__global__ void scan3_kernel(const int* __restrict__ part, const int* __restrict__ tops,
                             int* __restrict__ rowptr, int* __restrict__ cursor, int n)
{
    int i = blockIdx.x * 256 + threadIdx.x;
    if (i >= n) return;
    int add = (blockIdx.x > 0) ? tops[blockIdx.x - 1] : 0;
    int prev = (i > 0) ? ((threadIdx.x > 0) ? part[i - 1] + add
                                            : ((blockIdx.x > 0) ? tops[blockIdx.x - 1] : 0))
                       : 0;
    rowptr[i + 1] = part[i] + add;
    cursor[i] = prev;
    if (i == 0) rowptr[0] = 0;
}

// col entry: plain src row in combined table (p_rel folded into kr)
__global__ void scatter_kernel(const int* __restrict__ ti_src, const int* __restrict__ ti_dst,
                               const int* __restrict__ im_src, const int* __restrict__ im_dst,
                               const int* __restrict__ ub_src, const int* __restrict__ ub_dst,
                               const int* __restrict__ bu_src, const int* __restrict__ bu_dst,
                               int* __restrict__ cursor, int* __restrict__ col)
{
    int i = blockIdx.x * blockDim.x + threadIdx.x;
    if (i >= ETOT) return;
    int d, row;
    if (i < E_TI)                    { d = ti_dst[i];                  row = BASE_T + ti_src[i]; }
    else if (i < E_TI + E_IM)        { int e = i - E_TI;               row = BASE_G + im_src[e]; d = im_dst[e]; }
    else if (i < E_TI + E_IM + E_UB) { int e = i - E_TI - E_IM;        row = BASE_U + ub_src[e]; d = ub_dst[e]; }
    else                             { int e = i - E_TI - E_IM - E_UB; row = BASE_I + bu_src[e]; d = NI + bu_dst[e]; }
    int p = atomicAdd(&cursor[d], 1);
    col[p] = row;
}

// ------------- fused edge softmax-attention (online, one pass, x4 unroll) -------------
__global__ __launch_bounds__(256) void f12_kernel(
    const int* __restrict__ rowptr, const int* __restrict__ rowend,
    const int* __restrict__ col,
    const unsigned int* __restrict__ krw,   // bf16x2 per uint, row stride 64 (p_rel folded)
    const unsigned int* __restrict__ qb_i, const unsigned int* __restrict__ qb_u,
    const unsigned int* __restrict__ vrw,
    float* __restrict__ agg_i, float* __restrict__ agg_u)
{
    int wid = (blockIdx.x << 2) + (threadIdx.x >> 6);
    if (wid >= ND) return;
    const int l = threadIdx.x & 63;

    unsigned int qu = (wid < NI) ? qb_i[(size_t)wid * 64 + l]
                                 : qb_u[(size_t)(wid - NI) * 64 + l];
    const float qx = bflo(qu), qy = bfhi(qu);

    const int start = rowptr[wid], end = rowend[wid];
    float m = -3.0e38f, ax = 0.f, ay = 0.f, den = 0.f;

    int p = start;
    for (; p + 3 < end; p += 4) {
        int r0_ = col[p], r1_ = col[p + 1], r2_ = col[p + 2], r3_ = col[p + 3];
        unsigned int u0 = krw[(size_t)r0_ * 64 + l];
        unsigned int u1 = krw[(size_t)r1_ * 64 + l];
        unsigned int u2 = krw[(size_t)r2_ * 64 + l];
        unsigned int u3 = krw[(size_t)r3_ * 64 + l];
        unsigned int v0 = vrw[(size_t)r0_ * 64 + l];
        unsigned int v1 = vrw[(size_t)r1_ * 64 + l];
        unsigned int v2 = vrw[(size_t)r2_ * 64 + l];
        unsigned int v3 = vrw[(size_t)r3_ * 64 + l];
        float d0 = qx * bflo(u0) + qy * bfhi(u0);
        float d1 = qx * bflo(u1) + qy * bfhi(u1);
        float d2 = qx * bflo(u2) + qy * bfhi(u2);
        float d3 = qx * bflo(u3) + qy * bfhi(u3);
        d0 += __shfl_xor(d0, 1); d1 += __shfl_xor(d1, 1);
        d2 += __shfl_xor(d2, 1); d3 += __shfl_xor(d3, 1);
        d0 += __shfl_xor(d0, 2); d1 += __shfl_xor(d1, 2);
        d2 += __shfl_xor(d2, 2); d3 += __shfl_xor(d3, 2);
        d0 += __shfl_xor(d0, 4); d1 += __shfl_xor(d1, 4);
        d2 += __shfl_xor(d2, 4); d3 += __shfl_xor(d3, 4);
        float mn = fmaxf(m, fmaxf(fmaxf(d0, d1), fmaxf(d2, d3)));
        float s  = __expf(m - mn);
        float e0 = __expf(d0 - mn);
        float e1 = __expf(d1 - mn);
        float e2 = __expf(d2 - mn);
        float e3 = __expf(d3 - mn);
        ax = ax * s + e0 * bflo(v0) + e1 * bflo(v1) + e2 * bflo(v2) + e3 * bflo(v3);
        ay = ay * s + e0 * bfhi(v0) + e1 * bfhi(v1) + e2 * bfhi(v2) + e3 * bfhi(v3);
        den = den * s + (e0 + e1) + (e2 + e3);
        m = mn;
    }
    for (; p < end; ++p) {
        int r0_ = col[p];
        unsigned int u0 = krw[(size_t)r0_ * 64 + l];
        unsigned int v0 = vrw[(size_t)r0_ * 64 + l];
        float d0 = qx * bflo(u0) + qy * bfhi(u0);
        d0 += __shfl_xor(d0, 1);
        d0 += __shfl_xor(d0, 2);
        d0 += __shfl_xor(d0, 4);
        float mn = fmaxf(m, d0);
        float s  = __expf(m - mn);
        float e0 = __expf(d0 - mn);
        ax = ax * s + e0 * bflo(v0);
        ay = ay * s + e0 * bfhi(v0);
        den = den * s + e0;
        m = mn;
    }

    float inv = 1.f / (den + 1e-16f);
    float* dst = (wid < NI) ? agg_i + (size_t)wid * HIDN
                            : agg_u + (size_t)(wid - NI) * HIDN;
    *(float2*)(dst + 2 * l) = make_float2(ax * inv, ay * inv);
}

extern "C" void kernel_launch(void* const* d_in, const int* in_sizes, int n_in,
                              void* d_out, int out_size, void* d_ws, size_t ws_size,
                              hipStream_t stream)
{
    const float* x_user = (const float*)d_in[0];
    const float* x_item = (const float*)d_in[1];
    const float* x_taste= (const float*)d_in[2];
    const float* x_image= (const float*)d_in[3];
    const float* Wk     = (const float*)d_in[4];
    const float* bk     = (const float*)d_in[5];
    const float* Wq     = (const float*)d_in[6];
    const float* bq     = (const float*)d_in[7];
    const float* Wv     = (const float*)d_in[8];
    const float* bv     = (const float*)d_in[9];
    const float* a_rel  = (const float*)d_in[10];
    const float* m_rel  = (const float*)d_in[11];
    const float* p_rel  = (const float*)d_in[12];
    const float* Wo     = (const float*)d_in[13];
    const float* bo     = (const float*)d_in[14];
    const float* skip   = (const float*)d_in[15];
    const int* ti_src = (const int*)d_in[16];
    const int* ti_dst = (const int*)d_in[17];
    const int* im_src = (const int*)d_in[18];
    const int* im_dst = (const int*)d_in[19];
    const int* ub_src = (const int*)d_in[20];
    const int* ub_dst = (const int*)d_in[21];
    const int* bu_src = (const int*)d_in[22];
    const int* bu_dst = (const int*)d_in[23];

    float* ws = (float*)d_ws;
    float* outp = (float*)d_out;
    (void)in_sizes; (void)n_in; (void)out_size;

    // ---- workspace layout (floats) ----
    size_t off = 0;
    auto alloc = [&](size_t n) { size_t o = off; off += n; return o; };
    const size_t o_cw   = alloc((size_t)2 * 4 * 129 * 128);   // reused as deg[] after pack
    const size_t o_pkh  = alloc((size_t)NMAT * MATSZ / 2);
    const size_t o_pkl  = alloc((size_t)NMAT * MATSZ / 2);
    const size_t o_bias = alloc((size_t)NMAT * HIDN);
    const size_t o_krb  = alloc((size_t)(NU + NI + NT + NG) * HIDN / 2);  // bf16
    const size_t o_vrb  = alloc((size_t)(NU + NI + NT + NG) * HIDN / 2);  // bf16
    const size_t o_q_i  = alloc((size_t)NI * HIDN / 2);                   // bf16
    const size_t o_q_u  = alloc((size_t)NU * HIDN / 2);                   // bf16
    const size_t o_agg  = alloc((size_t)(NI + NU) * HIDN);
    const size_t o_int  = alloc((size_t)(ND + 1) + ND + 1024 + ETOT);

    if (ws_size < off * sizeof(float)) return;  // clean failure instead of OOB fault

    unsigned short* krb  = (unsigned short*)(ws + o_krb);
    unsigned short* vrb  = (unsigned short*)(ws + o_vrb);
    unsigned short* qb_i = (unsigned short*)(ws + o_q_i);
    unsigned short* qb_u = (unsigned short*)(ws + o_q_u);

    short* pkh  = (short*)(ws + o_pkh);
    short* pkl  = (short*)(ws + o_pkl);
    float* bias = ws + o_bias;

    int* deg    = (int*)(ws + o_cw);        // overlays cw (dead after pack)
    int* rowptr = (int*)(ws + o_int);
    int* cursor = rowptr + (ND + 1);
    int* tops   = cursor + ND;
    int* col    = tops + 1024;

    float* agg_i = ws + o_agg;
    float* agg_u = ws + o_agg + (size_t)NI * HIDN;

    // ---- 1. combined weights (p_rel folded into k) + MFMA pack ----
    {
        int total = 2 * 4 * 129 * 128;
        build_cw_kernel<<<(total + 255) / 256, 256, 0, stream>>>(
            Wk, bk, Wv, bv, a_rel, m_rel, p_rel, ws + o_cw);
        int ptotal = NMAT * MATSZ + NMAT * HIDN;
        pack_kernel<<<(ptotal + 255) / 256, 256, 0, stream>>>(
            ws + o_cw, Wq, bq, Wo, bo, pkh, pkl, bias);
    }

    // ---- 2. projections (B-stationary, bf16 outputs) ----
    mfma_proj_all<<<NBU + NBI + NBT + NBG, 256, 0, stream>>>(
        x_user, x_item, x_taste, x_image, pkh, pkl, bias,
        krb, vrb, qb_u, qb_i);

    // ---- 3. CSR build ----
    hipMemsetAsync(deg, 0, ND * sizeof(int), stream);
    hist_kernel<<<(ETOT + 255) / 256, 256, 0, stream>>>(ti_dst, im_dst, ub_dst, bu_dst, deg);
    const int NB1 = (ND + 255) / 256;
    scan1_kernel<<<NB1, 256, 0, stream>>>(deg, tops, ND);
    scan2_kernel<<<1, 1024, 0, stream>>>(tops, NB1);
    scan3_kernel<<<NB1, 256, 0, stream>>>(deg, tops, rowptr, cursor, ND);
    scatter_kernel<<<(ETOT + 255) / 256, 256, 0, stream>>>(
        ti_src, ti_dst, im_src, im_dst, ub_src, ub_dst, bu_src, bu_dst, cursor, col);
    // after scatter, cursor[d] == row end

    // ---- 4. fused online-softmax edge aggregation ----
    const int NBW = (ND + 3) / 4;
    f12_kernel<<<NBW, 256, 0, stream>>>(
        rowptr, cursor, col,
        (const unsigned int*)krb, (const unsigned int*)qb_i, (const unsigned int*)qb_u,
        (const unsigned int*)vrb,
        agg_i, agg_u);

    // ---- 5. epilogue (B-stationary) ----
    mfma_out_all<<<NBI + NBU, 256, 0, stream>>>(
        agg_i, agg_u, pkh, pkl, bias, x_item, x_user, skip, outp);
}

// Round 14
// 297.984 us; speedup vs baseline: 1.5101x; 1.1020x over previous
//
#include <hip/hip_runtime.h>
#include <math.h>

// ---------------------------------------------------------------------------
// MultiModalFusionGAT — round 14
//   = round 13 (B-stationary MFMA proj/epilogue, bf16 tables, p_rel folded,
//     online-softmax x4-unrolled edge kernel)
//   + build_cw folded into pack (computes combined weights inline)
//   + deg-zero fused into pack; hist fused into proj launch (tail blocks)
//   + agg stored as bf16 (f12 writes packed, epilogue stages from bf16)
//   Launches: 8 (was 11 + memset)
// ---------------------------------------------------------------------------

namespace {
constexpr int HIDN  = 128;
constexpr int NHEAD = 8;

constexpr int NU = 20000, NI = 50000, NT = 50000, NG = 50000;
constexpr int E_TI = 50000, E_IM = 50000, E_UB = 500000, E_BU = 500000;
constexpr int ETOT = E_TI + E_IM + E_UB + E_BU;   // 1,100,000
constexpr int ND   = NI + NU;                     // dst nodes: items then users

constexpr int BASE_U = 0;
constexpr int BASE_I = NU;
constexpr int BASE_T = NU + NI;
constexpr int BASE_G = NU + NI + NT;

constexpr int NMAT = 12;           // 0..3 k, 4..7 v, 8/9 q(user,item), 10/11 Wo(item,user)
constexpr int MATSZ = 128 * 128;
constexpr int SU = 136;            // ushort stride for hi/lo LDS planes

constexpr int NBU = (NU + 63) / 64;
constexpr int NBI = (NI + 63) / 64;
constexpr int NBT = (NT + 63) / 64;
constexpr int NBG = (NG + 63) / 64;
constexpr int NPROJ = NBU + NBI + NBT + NBG;      // 2620
constexpr int NBH   = (ETOT + 255) / 256;         // hist blocks appended
}

typedef __attribute__((ext_vector_type(8))) short short8v;
typedef __attribute__((ext_vector_type(4))) float f32x4;
typedef __attribute__((ext_vector_type(4))) unsigned short ushort4v;

__device__ __forceinline__ unsigned short bf16rne(float f) {
    unsigned u = __float_as_uint(f);
    unsigned r = (u + 0x7fffu + ((u >> 16) & 1u)) >> 16;
    return (unsigned short)r;
}
__device__ __forceinline__ float bf16f(unsigned short h) {
    return __uint_as_float(((unsigned)h) << 16);
}
__device__ __forceinline__ float bflo(unsigned int u) { return __uint_as_float(u << 16); }
__device__ __forceinline__ float bfhi(unsigned int u) { return __uint_as_float(u & 0xffff0000u); }

// pack: computes combined (rel-fused, p_rel-scaled) weights inline, packs all 12
// mats to MFMA fragment order (bf16 hi/lo), builds bias table, zeroes deg.
__global__ void pack_kernel(const float* __restrict__ Wk, const float* __restrict__ bk,
                            const float* __restrict__ Wv, const float* __restrict__ bv,
                            const float* __restrict__ a_rel, const float* __restrict__ m_rel,
                            const float* __restrict__ p_rel,
                            const float* __restrict__ Wq, const float* __restrict__ bq,
                            const float* __restrict__ Wo, const float* __restrict__ bo,
                            short* __restrict__ pkh, short* __restrict__ pkl,
                            float* __restrict__ bias, int* __restrict__ deg)
{
    const int NW = NMAT * MATSZ;
    const int NB = NMAT * HIDN;
    int idx = blockIdx.x * blockDim.x + threadIdx.x;
    if (idx < NW) {
        int mat = idx >> 14;
        int rem = idx & (MATSZ - 1);
        int i    = rem & 7;
        int lane = (rem >> 3) & 63;
        int ct   = (rem >> 9) & 7;
        int ks   = rem >> 12;
        int k   = ks * 32 + ((lane >> 4) & 3) * 8 + i;
        int col = ct * 16 + (lane & 15);
        float v;
        if (mat < 8) {
            int which = mat >> 2;                 // 0 = k-side, 1 = v-side
            int tt = mat & 3;
            const int et_map[4] = {2, 3, 0, 1};
            int et = et_map[tt];
            const float* W = (which == 0 ? Wk : Wv) + (size_t)tt * MATSZ;
            const float* A = (which == 0 ? a_rel : m_rel) + (size_t)et * NHEAD * 256;
            int h = ct, e2 = col & 15;
            float s = 0.f;
#pragma unroll
            for (int d = 0; d < 16; ++d)
                s = fmaf(W[(size_t)k * HIDN + h * 16 + d], A[h * 256 + d * 16 + e2], s);
            if (which == 0) s *= p_rel[et * NHEAD + h] * 0.25f;
            v = s;
        } else if (mat < 10) {
            v = Wq[(size_t)(mat - 8) * MATSZ + (size_t)k * HIDN + col];
        } else {
            v = Wo[(size_t)(mat - 10) * MATSZ + (size_t)k * HIDN + col];
        }
        unsigned short hb = bf16rne(v);
        pkh[idx] = (short)hb;
        pkl[idx] = (short)bf16rne(v - bf16f(hb));
    } else if (idx < NW + NB) {
        int b = idx - NW;
        int mat = b >> 7, col = b & 127;
        float v;
        if (mat < 8) {
            int which = mat >> 2;
            int tt = mat & 3;
            const int et_map[4] = {2, 3, 0, 1};
            int et = et_map[tt];
            const float* bb = (which == 0 ? bk : bv) + tt * HIDN;
            const float* A  = (which == 0 ? a_rel : m_rel) + (size_t)et * NHEAD * 256;
            int h = col >> 4, e2 = col & 15;
            float s = 0.f;
#pragma unroll
            for (int d = 0; d < 16; ++d)
                s = fmaf(bb[h * 16 + d], A[h * 256 + d * 16 + e2], s);
            if (which == 0) s *= p_rel[et * NHEAD + h] * 0.25f;
            v = s;
        } else if (mat < 10) v = bq[(mat - 8) * HIDN + col];
        else                 v = bo[(mat - 10) * HIDN + col];
        bias[b] = v;
    } else if (idx < NW + NB + ND) {
        deg[idx - NW - NB] = 0;
    }
}

// B-stationary projections (+ fused edge histogram in tail blocks).
__global__ __launch_bounds__(256) void mfma_proj_all(
    const float* __restrict__ xu, const float* __restrict__ xi,
    const float* __restrict__ xt, const float* __restrict__ xg,
    const short* __restrict__ pkh, const short* __restrict__ pkl,
    const float* __restrict__ bias,
    unsigned short* __restrict__ krb, unsigned short* __restrict__ vrb,
    unsigned short* __restrict__ qb_u, unsigned short* __restrict__ qb_i,
    const int* __restrict__ ti_dst, const int* __restrict__ im_dst,
    const int* __restrict__ ub_dst, const int* __restrict__ bu_dst,
    int* __restrict__ deg)
{
    int b = blockIdx.x;
    if (b >= NPROJ) {
        // ---- fused histogram blocks ----
        int i = (b - NPROJ) * 256 + threadIdx.x;
        if (i < ETOT) {
            int d;
            if (i < E_TI)                     d = ti_dst[i];
            else if (i < E_TI + E_IM)         d = im_dst[i - E_TI];
            else if (i < E_TI + E_IM + E_UB)  d = ub_dst[i - E_TI - E_IM];
            else                              d = NI + bu_dst[i - E_TI - E_IM - E_UB];
            atomicAdd(&deg[d], 1);
        }
        return;
    }

    int seg, bloc;
    if (b < NBU)                  { seg = 0; bloc = b; }
    else if (b < NBU + NBI)       { seg = 1; bloc = b - NBU; }
    else if (b < NBU + NBI + NBT) { seg = 2; bloc = b - NBU - NBI; }
    else                          { seg = 3; bloc = b - NBU - NBI - NBT; }
    const float* x = (seg == 0) ? xu : (seg == 1) ? xi : (seg == 2) ? xt : xg;
    const int M     = (seg == 0) ? NU : (seg == 1) ? NI : (seg == 2) ? NT : NG;
    const int rbase = (seg == 0) ? BASE_U : (seg == 1) ? BASE_I : (seg == 2) ? BASE_T : BASE_G;
    unsigned short* qp = (seg == 0) ? qb_u : (seg == 1) ? qb_i : nullptr;

    __shared__ unsigned short hs[64 * SU];
    __shared__ unsigned short ls[64 * SU];
    const int t  = threadIdx.x;
    const int r0 = bloc * 64;
    const int rows = min(64, M - r0);

#pragma unroll
    for (int p = 0; p < 8; ++p) {
        int f = p * 256 + t;
        int row = f >> 5, c4 = f & 31;
        float4 v = make_float4(0.f, 0.f, 0.f, 0.f);
        if (row < rows) v = *(const float4*)(x + (size_t)(r0 + row) * HIDN + c4 * 4);
        float vv[4] = {v.x, v.y, v.z, v.w};
        ushort4v hq, lq;
#pragma unroll
        for (int i = 0; i < 4; ++i) {
            unsigned short hb = bf16rne(vv[i]);
            hq[i] = hb;
            lq[i] = bf16rne(vv[i] - bf16f(hb));
        }
        *(ushort4v*)&hs[row * SU + c4 * 4] = hq;
        *(ushort4v*)&ls[row * SU + c4 * 4] = lq;
    }
    __syncthreads();

    const int l = t & 63, w = t >> 6;
    const int kgrp = l >> 4;
    const int ct0  = 2 * w;
    const int ccol = l & 15;

    for (int mi = 0; mi < 3; ++mi) {
        if (mi == 2 && qp == nullptr) break;
        const int mat = (mi == 0) ? seg : (mi == 1) ? (4 + seg) : (8 + seg);
        const short8v* bh = (const short8v*)(pkh + (size_t)mat * MATSZ);
        const short8v* bl = (const short8v*)(pkl + (size_t)mat * MATSZ);
        const float*   bs = bias + mat * HIDN;

        short8v B1[4][2], B2[4][2];
#pragma unroll
        for (int ks = 0; ks < 4; ++ks) {
#pragma unroll
            for (int c = 0; c < 2; ++c) {
                B1[ks][c] = bh[(ks * 8 + ct0 + c) * 64 + l];
                if (mi == 2) B2[ks][c] = bl[(ks * 8 + ct0 + c) * 64 + l];
            }
        }

        const float bv0 = bs[(ct0 + 0) * 16 + ccol];
        const float bv1 = bs[(ct0 + 1) * 16 + ccol];

        for (int rt = 0; rt < 4; ++rt) {
            f32x4 a0, a1;
            a0[0]=0.f;a0[1]=0.f;a0[2]=0.f;a0[3]=0.f;
            a1[0]=0.f;a1[1]=0.f;a1[2]=0.f;a1[3]=0.f;
            const int arow = rt * 16 + ccol;
#pragma unroll
            for (int ks = 0; ks < 4; ++ks) {
                short8v ah = *(const short8v*)&hs[arow * SU + ks * 32 + kgrp * 8];
                short8v al = *(const short8v*)&ls[arow * SU + ks * 32 + kgrp * 8];
                a0 = __builtin_amdgcn_mfma_f32_16x16x32_bf16(ah, B1[ks][0], a0, 0, 0, 0);
                a1 = __builtin_amdgcn_mfma_f32_16x16x32_bf16(ah, B1[ks][1], a1, 0, 0, 0);
                a0 = __builtin_amdgcn_mfma_f32_16x16x32_bf16(al, B1[ks][0], a0, 0, 0, 0);
                a1 = __builtin_amdgcn_mfma_f32_16x16x32_bf16(al, B1[ks][1], a1, 0, 0, 0);
                if (mi == 2) {
                    a0 = __builtin_amdgcn_mfma_f32_16x16x32_bf16(ah, B2[ks][0], a0, 0, 0, 0);
                    a1 = __builtin_amdgcn_mfma_f32_16x16x32_bf16(ah, B2[ks][1], a1, 0, 0, 0);
                }
            }
            const int crow = r0 + rt * 16 + kgrp * 4;
            unsigned short* dst = (mi == 0) ? krb + (size_t)rbase * HIDN
                                : (mi == 1) ? vrb + (size_t)rbase * HIDN
                                            : qp;
#pragma unroll
            for (int j = 0; j < 4; ++j) {
                int grow = crow + j;
                if (grow < M) {
                    size_t o = (size_t)grow * HIDN;
                    dst[o + (ct0 + 0) * 16 + ccol] = bf16rne(a0[j] + bv0);
                    dst[o + (ct0 + 1) * 16 + ccol] = bf16rne(a1[j] + bv1);
                }
            }
        }
    }
}

// B-stationary epilogue (agg read as bf16, full 3-term split, fp32 out).
__global__ __launch_bounds__(256) void mfma_out_all(
    const unsigned short* __restrict__ agg_i, const unsigned short* __restrict__ agg_u,
    const short* __restrict__ pkh, const short* __restrict__ pkl,
    const float* __restrict__ bias,
    const float* __restrict__ x_item, const float* __restrict__ x_user,
    const float* __restrict__ skip_ptr,
    float* __restrict__ outp)
{
    int b = blockIdx.x;
    int seg = (b < NBI) ? 0 : 1;
    int bloc = (seg == 0) ? b : b - NBI;
    const unsigned short* agg = (seg == 0) ? agg_i : agg_u;
    const float* xin = (seg == 0) ? x_item : x_user;
    const int M = (seg == 0) ? NI : NU;
    const int mat = 10 + seg;
    float* out = (seg == 0) ? outp : outp + (size_t)NI * HIDN;

    __shared__ unsigned short hs[64 * SU];
    __shared__ unsigned short ls[64 * SU];
    const int t  = threadIdx.x;
    const int r0 = bloc * 64;
    const int rows = min(64, M - r0);

#pragma unroll
    for (int p = 0; p < 8; ++p) {
        int f = p * 256 + t;
        int row = f >> 5, c4 = f & 31;      // c4: group of 4 bf16
        float vv[4] = {0.f, 0.f, 0.f, 0.f};
        if (row < rows) {
            uint2 u = *(const uint2*)(agg + (size_t)(r0 + row) * HIDN + c4 * 4);
            vv[0] = bflo(u.x); vv[1] = bfhi(u.x);
            vv[2] = bflo(u.y); vv[3] = bfhi(u.y);
        }
        ushort4v hq, lq;
#pragma unroll
        for (int i = 0; i < 4; ++i) {
            float g = 0.5f * vv[i] * (1.0f + erff(vv[i] * 0.70710678118654752440f));
            unsigned short hb = bf16rne(g);
            hq[i] = hb;
            lq[i] = bf16rne(g - bf16f(hb));
        }
        *(ushort4v*)&hs[row * SU + c4 * 4] = hq;
        *(ushort4v*)&ls[row * SU + c4 * 4] = lq;
    }
    __syncthreads();

    const int l = t & 63, w = t >> 6;
    const int kgrp = l >> 4;
    const int ct0  = 2 * w;
    const int ccol = l & 15;

    const short8v* bh = (const short8v*)(pkh + (size_t)mat * MATSZ);
    const short8v* bl = (const short8v*)(pkl + (size_t)mat * MATSZ);
    const float*   bs = bias + mat * HIDN;

    short8v B1[4][2], B2[4][2];
#pragma unroll
    for (int ks = 0; ks < 4; ++ks) {
#pragma unroll
        for (int c = 0; c < 2; ++c) {
            B1[ks][c] = bh[(ks * 8 + ct0 + c) * 64 + l];
            B2[ks][c] = bl[(ks * 8 + ct0 + c) * 64 + l];
        }
    }

    const float gate = 1.f / (1.f + expf(-skip_ptr[seg]));
    const float og = 1.f - gate;
    const float bv0 = bs[(ct0 + 0) * 16 + ccol];
    const float bv1 = bs[(ct0 + 1) * 16 + ccol];

    for (int rt = 0; rt < 4; ++rt) {
        f32x4 a0, a1;
        a0[0]=0.f;a0[1]=0.f;a0[2]=0.f;a0[3]=0.f;
        a1[0]=0.f;a1[1]=0.f;a1[2]=0.f;a1[3]=0.f;
        const int arow = rt * 16 + ccol;
#pragma unroll
        for (int ks = 0; ks < 4; ++ks) {
            short8v ah = *(const short8v*)&hs[arow * SU + ks * 32 + kgrp * 8];
            short8v al = *(const short8v*)&ls[arow * SU + ks * 32 + kgrp * 8];
            a0 = __builtin_amdgcn_mfma_f32_16x16x32_bf16(ah, B1[ks][0], a0, 0, 0, 0);
            a1 = __builtin_amdgcn_mfma_f32_16x16x32_bf16(ah, B1[ks][1], a1, 0, 0, 0);
            a0 = __builtin_amdgcn_mfma_f32_16x16x32_bf16(al, B1[ks][0], a0, 0, 0, 0);
            a1 = __builtin_amdgcn_mfma_f32_16x16x32_bf16(al, B1[ks][1], a1, 0, 0, 0);
            a0 = __builtin_amdgcn_mfma_f32_16x16x32_bf16(ah, B2[ks][0], a0, 0, 0, 0);
            a1 = __builtin_amdgcn_mfma_f32_16x16x32_bf16(ah, B2[ks][1], a1, 0, 0, 0);
        }
        const int crow = r0 + rt * 16 + kgrp * 4;
#pragma unroll
        for (int j = 0; j < 4; ++j) {
            int grow = crow + j;
            if (grow < M) {
                size_t o = (size_t)grow * HIDN;
                size_t o0 = o + (ct0 + 0) * 16 + ccol;
                size_t o1 = o + (ct0 + 1) * 16 + ccol;
                out[o0] = gate * (a0[j] + bv0) + og * xin[o0];
                out[o1] = gate * (a1[j] + bv1) + og * xin[o1];
            }
        }
    }
}

// ----------------------- CSR scans + scatter -----------------------

__global__ void scan1_kernel(int* __restrict__ deg, int* __restrict__ tops, int n)
{
    __shared__ int sh[256];
    int i = blockIdx.x * 256 + threadIdx.x;
    int v = (i < n) ? deg[i] : 0;
    sh[threadIdx.x] = v;
    __syncthreads();
    for (int o = 1; o < 256; o <<= 1) {
        int t = (threadIdx.x >= o) ? sh[threadIdx.x - o] : 0;
        __syncthreads();
        sh[threadIdx.x] += t;
        __syncthreads();
    }
    if (i < n) deg[i] = sh[threadIdx.x];
    if (threadIdx.x == 255) tops[blockIdx.x] = sh[255];
}

__global__ void scan2_kernel(int* __restrict__ tops, int nb)
{
    __shared__ int sh[1024];
    int v = (threadIdx.x < nb) ? tops[threadIdx.x] : 0;
    sh[threadIdx.x] = v;
    __syncthreads();
    for (int o = 1; o < 1024; o <<= 1) {
        int t = (threadIdx.x >= o) ? sh[threadIdx.x - o] : 0;
        __syncthreads();
        sh[threadIdx.x] += t;
        __syncthreads();
    }
    if (threadIdx.x < nb) tops[threadIdx.x] = sh[threadIdx.x];
}

__global__ void scan3_kernel(const int* __restrict__ part, const int* __restrict__ tops,
                             int* __restrict__ rowptr, int* __restrict__ cursor, int n)
{
    int i = blockIdx.x * 256 + threadIdx.x;
    if (i >= n) return;
    int add = (blockIdx.x > 0) ? tops[blockIdx.x - 1] : 0;
    int prev = (i > 0) ? ((threadIdx.x > 0) ? part[i - 1] + add
                                            : ((blockIdx.x > 0) ? tops[blockIdx.x - 1] : 0))
                       : 0;
    rowptr[i + 1] = part[i] + add;
    cursor[i] = prev;
    if (i == 0) rowptr[0] = 0;
}

// col entry: plain src row in combined table (p_rel folded into kr)
__global__ void scatter_kernel(const int* __restrict__ ti_src, const int* __restrict__ ti_dst,
                               const int* __restrict__ im_src, const int* __restrict__ im_dst,
                               const int* __restrict__ ub_src, const int* __restrict__ ub_dst,
                               const int* __restrict__ bu_src, const int* __restrict__ bu_dst,
                               int* __restrict__ cursor, int* __restrict__ col)
{
    int i = blockIdx.x * blockDim.x + threadIdx.x;
    if (i >= ETOT) return;
    int d, row;
    if (i < E_TI)                    { d = ti_dst[i];                  row = BASE_T + ti_src[i]; }
    else if (i < E_TI + E_IM)        { int e = i - E_TI;               row = BASE_G + im_src[e]; d = im_dst[e]; }
    else if (i < E_TI + E_IM + E_UB) { int e = i - E_TI - E_IM;        row = BASE_U + ub_src[e]; d = ub_dst[e]; }
    else                             { int e = i - E_TI - E_IM - E_UB; row = BASE_I + bu_src[e]; d = NI + bu_dst[e]; }
    int p = atomicAdd(&cursor[d], 1);
    col[p] = row;
}

// ------------- fused edge softmax-attention (online, one pass, x4 unroll) -------------
__global__ __launch_bounds__(256) void f12_kernel(
    const int* __restrict__ rowptr, const int* __restrict__ rowend,
    const int* __restrict__ col,
    const unsigned int* __restrict__ krw,   // bf16x2 per uint, row stride 64 (p_rel folded)
    const unsigned int* __restrict__ qb_i, const unsigned int* __restrict__ qb_u,
    const unsigned int* __restrict__ vrw,
    unsigned short* __restrict__ agg_i, unsigned short* __restrict__ agg_u)
{
    int wid = (blockIdx.x << 2) + (threadIdx.x >> 6);
    if (wid >= ND) return;
    const int l = threadIdx.x & 63;

    unsigned int qu = (wid < NI) ? qb_i[(size_t)wid * 64 + l]
                                 : qb_u[(size_t)(wid - NI) * 64 + l];
    const float qx = bflo(qu), qy = bfhi(qu);

    const int start = rowptr[wid], end = rowend[wid];
    float m = -3.0e38f, ax = 0.f, ay = 0.f, den = 0.f;

    int p = start;
    for (; p + 3 < end; p += 4) {
        int r0_ = col[p], r1_ = col[p + 1], r2_ = col[p + 2], r3_ = col[p + 3];
        unsigned int u0 = krw[(size_t)r0_ * 64 + l];
        unsigned int u1 = krw[(size_t)r1_ * 64 + l];
        unsigned int u2 = krw[(size_t)r2_ * 64 + l];
        unsigned int u3 = krw[(size_t)r3_ * 64 + l];
        unsigned int v0 = vrw[(size_t)r0_ * 64 + l];
        unsigned int v1 = vrw[(size_t)r1_ * 64 + l];
        unsigned int v2 = vrw[(size_t)r2_ * 64 + l];
        unsigned int v3 = vrw[(size_t)r3_ * 64 + l];
        float d0 = qx * bflo(u0) + qy * bfhi(u0);
        float d1 = qx * bflo(u1) + qy * bfhi(u1);
        float d2 = qx * bflo(u2) + qy * bfhi(u2);
        float d3 = qx * bflo(u3) + qy * bfhi(u3);
        d0 += __shfl_xor(d0, 1); d1 += __shfl_xor(d1, 1);
        d2 += __shfl_xor(d2, 1); d3 += __shfl_xor(d3, 1);
        d0 += __shfl_xor(d0, 2); d1 += __shfl_xor(d1, 2);
        d2 += __shfl_xor(d2, 2); d3 += __shfl_xor(d3, 2);
        d0 += __shfl_xor(d0, 4); d1 += __shfl_xor(d1, 4);
        d2 += __shfl_xor(d2, 4); d3 += __shfl_xor(d3, 4);
        float mn = fmaxf(m, fmaxf(fmaxf(d0, d1), fmaxf(d2, d3)));
        float s  = __expf(m - mn);
        float e0 = __expf(d0 - mn);
        float e1 = __expf(d1 - mn);
        float e2 = __expf(d2 - mn);
        float e3 = __expf(d3 - mn);
        ax = ax * s + e0 * bflo(v0) + e1 * bflo(v1) + e2 * bflo(v2) + e3 * bflo(v3);
        ay = ay * s + e0 * bfhi(v0) + e1 * bfhi(v1) + e2 * bfhi(v2) + e3 * bfhi(v3);
        den = den * s + (e0 + e1) + (e2 + e3);
        m = mn;
    }
    for (; p < end; ++p) {
        int r0_ = col[p];
        unsigned int u0 = krw[(size_t)r0_ * 64 + l];
        unsigned int v0 = vrw[(size_t)r0_ * 64 + l];
        float d0 = qx * bflo(u0) + qy * bfhi(u0);
        d0 += __shfl_xor(d0, 1);
        d0 += __shfl_xor(d0, 2);
        d0 += __shfl_xor(d0, 4);
        float mn = fmaxf(m, d0);
        float s  = __expf(m - mn);
        float e0 = __expf(d0 - mn);
        ax = ax * s + e0 * bflo(v0);
        ay = ay * s + e0 * bfhi(v0);
        den = den * s + e0;
        m = mn;
    }

    float inv = 1.f / (den + 1e-16f);
    unsigned short* dst = (wid < NI) ? agg_i + (size_t)wid * HIDN
                                     : agg_u + (size_t)(wid - NI) * HIDN;
    unsigned int packed = (unsigned)bf16rne(ax * inv) | ((unsigned)bf16rne(ay * inv) << 16);
    *(unsigned int*)(dst + 2 * l) = packed;
}

extern "C" void kernel_launch(void* const* d_in, const int* in_sizes, int n_in,
                              void* d_out, int out_size, void* d_ws, size_t ws_size,
                              hipStream_t stream)
{
    const float* x_user = (const float*)d_in[0];
    const float* x_item = (const float*)d_in[1];
    const float* x_taste= (const float*)d_in[2];
    const float* x_image= (const float*)d_in[3];
    const float* Wk     = (const float*)d_in[4];
    const float* bk     = (const float*)d_in[5];
    const float* Wq     = (const float*)d_in[6];
    const float* bq     = (const float*)d_in[7];
    const float* Wv     = (const float*)d_in[8];
    const float* bv     = (const float*)d_in[9];
    const float* a_rel  = (const float*)d_in[10];
    const float* m_rel  = (const float*)d_in[11];
    const float* p_rel  = (const float*)d_in[12];
    const float* Wo     = (const float*)d_in[13];
    const float* bo     = (const float*)d_in[14];
    const float* skip   = (const float*)d_in[15];
    const int* ti_src = (const int*)d_in[16];
    const int* ti_dst = (const int*)d_in[17];
    const int* im_src = (const int*)d_in[18];
    const int* im_dst = (const int*)d_in[19];
    const int* ub_src = (const int*)d_in[20];
    const int* ub_dst = (const int*)d_in[21];
    const int* bu_src = (const int*)d_in[22];
    const int* bu_dst = (const int*)d_in[23];

    float* ws = (float*)d_ws;
    float* outp = (float*)d_out;
    (void)in_sizes; (void)n_in; (void)out_size;

    // ---- workspace layout (floats) ----
    size_t off = 0;
    auto alloc = [&](size_t n) { size_t o = off; off += n; return o; };
    const size_t o_pkh  = alloc((size_t)NMAT * MATSZ / 2);
    const size_t o_pkl  = alloc((size_t)NMAT * MATSZ / 2);
    const size_t o_bias = alloc((size_t)NMAT * HIDN);
    const size_t o_krb  = alloc((size_t)(NU + NI + NT + NG) * HIDN / 2);  // bf16
    const size_t o_vrb  = alloc((size_t)(NU + NI + NT + NG) * HIDN / 2);  // bf16
    const size_t o_q_i  = alloc((size_t)NI * HIDN / 2);                   // bf16
    const size_t o_q_u  = alloc((size_t)NU * HIDN / 2);                   // bf16
    const size_t o_agg  = alloc((size_t)(NI + NU) * HIDN / 2);            // bf16
    const size_t o_int  = alloc((size_t)(ND + 1) + ND + 1024 + ETOT + ND);

    if (ws_size < off * sizeof(float)) return;  // clean failure instead of OOB fault

    unsigned short* krb  = (unsigned short*)(ws + o_krb);
    unsigned short* vrb  = (unsigned short*)(ws + o_vrb);
    unsigned short* qb_i = (unsigned short*)(ws + o_q_i);
    unsigned short* qb_u = (unsigned short*)(ws + o_q_u);

    short* pkh  = (short*)(ws + o_pkh);
    short* pkl  = (short*)(ws + o_pkl);
    float* bias = ws + o_bias;

    int* rowptr = (int*)(ws + o_int);
    int* cursor = rowptr + (ND + 1);
    int* tops   = cursor + ND;
    int* col    = tops + 1024;
    int* deg    = col + ETOT;

    unsigned short* agg_i = (unsigned short*)(ws + o_agg);
    unsigned short* agg_u = agg_i + (size_t)NI * HIDN;

    // ---- 1. pack (combined weights computed inline) + deg zero ----
    {
        int ptotal = NMAT * MATSZ + NMAT * HIDN + ND;
        pack_kernel<<<(ptotal + 255) / 256, 256, 0, stream>>>(
            Wk, bk, Wv, bv, a_rel, m_rel, p_rel, Wq, bq, Wo, bo,
            pkh, pkl, bias, deg);
    }

    // ---- 2. projections + fused histogram ----
    mfma_proj_all<<<NPROJ + NBH, 256, 0, stream>>>(
        x_user, x_item, x_taste, x_image, pkh, pkl, bias,
        krb, vrb, qb_u, qb_i,
        ti_dst, im_dst, ub_dst, bu_dst, deg);

    // ---- 3. CSR scans + scatter ----
    const int NB1 = (ND + 255) / 256;
    scan1_kernel<<<NB1, 256, 0, stream>>>(deg, tops, ND);
    scan2_kernel<<<1, 1024, 0, stream>>>(tops, NB1);
    scan3_kernel<<<NB1, 256, 0, stream>>>(deg, tops, rowptr, cursor, ND);
    scatter_kernel<<<(ETOT + 255) / 256, 256, 0, stream>>>(
        ti_src, ti_dst, im_src, im_dst, ub_src, ub_dst, bu_src, bu_dst, cursor, col);
    // after scatter, cursor[d] == row end

    // ---- 4. fused online-softmax edge aggregation (bf16 agg out) ----
    const int NBW = (ND + 3) / 4;
    f12_kernel<<<NBW, 256, 0, stream>>>(
        rowptr, cursor, col,
        (const unsigned int*)krb, (const unsigned int*)qb_i, (const unsigned int*)qb_u,
        (const unsigned int*)vrb,
        agg_i, agg_u);

    // ---- 5. epilogue (B-stationary, bf16 agg in) ----
    mfma_out_all<<<NBI + NBU, 256, 0, stream>>>(
        agg_i, agg_u, pkh, pkl, bias, x_item, x_user, skip, outp);
}